// Round 2
// baseline (440.256 us; speedup 1.0000x reference)
//
#include <hip/hip_runtime.h>

#define NB   32      // graphs
#define NPER 512     // nodes per graph
#define NN   16384   // total nodes
#define EE   262144  // edges
#define DD   128     // D_IN == D_OUT
#define AS   2048    // total clusters
#define KC   64      // clusters per graph

// ---------------- CSR build ----------------
__global__ void count_kernel(const int* __restrict__ edst, int* __restrict__ cnt) {
    int e = blockIdx.x * 256 + threadIdx.x;
    atomicAdd(&cnt[edst[e]], 1);
}

__global__ void scan_kernel(const int* __restrict__ cnt, int* __restrict__ off,
                            int* __restrict__ cursor) {
    __shared__ int sums[256];
    int t = threadIdx.x;
    int base = t * 64;
    int sum = 0;
    for (int i = 0; i < 64; i++) sum += cnt[base + i];
    sums[t] = sum;
    __syncthreads();
    for (int d = 1; d < 256; d <<= 1) {
        int add = (t >= d) ? sums[t - d] : 0;
        __syncthreads();
        sums[t] += add;
        __syncthreads();
    }
    int run = (t == 0) ? 0 : sums[t - 1];
    for (int i = 0; i < 64; i++) {
        off[base + i] = run;
        cursor[base + i] = run;
        run += cnt[base + i];
    }
    if (t == 255) off[NN] = run;
}

__global__ void scatter_kernel(const int* __restrict__ esrc, const int* __restrict__ edst,
                               int* __restrict__ cursor, int* __restrict__ csr) {
    int e = blockIdx.x * 256 + threadIdx.x;
    int p = atomicAdd(&cursor[edst[e]], 1);
    csr[p] = esrc[e];
}

// ---------------- neighbor mean ----------------
__global__ void agg_h_kernel(const float* __restrict__ h, const int* __restrict__ off,
                             const int* __restrict__ csr, float* __restrict__ hn) {
    int n = blockIdx.x;
    int t = threadIdx.x;  // 128
    int b0 = off[n], b1 = off[n + 1];
    float a = 0.f;
    for (int i = b0; i < b1; i++) {
        int s = csr[i];
        a += h[(size_t)s * DD + t];
    }
    float deg = fmaxf((float)(b1 - b0), 1.0f);
    hn[(size_t)n * DD + t] = a / deg;
}

// ---------------- feat GEMM + L2norm + relu ----------------
__global__ void feat_kernel(const float* __restrict__ h, const float* __restrict__ hn,
                            const float* __restrict__ W, const float* __restrict__ bias,
                            float* __restrict__ feat) {
    __shared__ float lds[8][256];
    __shared__ float red[2];
    int t = threadIdx.x;  // 128
    int base = blockIdx.x * 8;
    for (int j = 0; j < 8; j++) {
        int n = base + j;
        lds[j][t] = h[(size_t)n * DD + t];
        lds[j][128 + t] = hn[(size_t)n * DD + t];
    }
    __syncthreads();
    float acc[8];
    float bb = bias[t];
#pragma unroll
    for (int j = 0; j < 8; j++) acc[j] = bb;
    for (int k = 0; k < 256; k++) {
        float w = W[k * DD + t];
#pragma unroll
        for (int j = 0; j < 8; j++) acc[j] += lds[j][k] * w;
    }
    for (int j = 0; j < 8; j++) {
        float sq = acc[j] * acc[j];
#pragma unroll
        for (int d = 32; d > 0; d >>= 1) sq += __shfl_xor(sq, d, 64);
        if ((t & 63) == 0) red[t >> 6] = sq;
        __syncthreads();
        float norm = sqrtf(red[0] + red[1]);
        float r = 1.0f / fmaxf(norm, 1e-12f);
        float v = acc[j] * r;
        feat[(size_t)(base + j) * DD + t] = fmaxf(v, 0.0f);
        __syncthreads();
    }
}

// ---------------- pool GEMM: full 2048-col norm + keep 64 in-graph cols ----------------
__global__ void pool_kernel(const float* __restrict__ h, const float* __restrict__ hn,
                            const float* __restrict__ Wp, const float* __restrict__ bp,
                            float* __restrict__ raws) {
    __shared__ float lds[8][256];
    __shared__ float red[4];
    int t = threadIdx.x;  // 256; thread owns cols 8t..8t+7
    int base = blockIdx.x * 8;
    int g = base / NPER;  // all 8 nodes same graph (512 % 8 == 0)
    for (int j = 0; j < 8; j++) {
        int n = base + j;
        if (t < 128) lds[j][t] = h[(size_t)n * DD + t];
        else         lds[j][t] = hn[(size_t)n * DD + (t - 128)];
    }
    __syncthreads();

    float acc[8][8];
    {
        const float4* bprow = reinterpret_cast<const float4*>(bp);
        float4 blo = bprow[2 * t], bhi = bprow[2 * t + 1];
#pragma unroll
        for (int j = 0; j < 8; j++) {
            acc[j][0] = blo.x; acc[j][1] = blo.y; acc[j][2] = blo.z; acc[j][3] = blo.w;
            acc[j][4] = bhi.x; acc[j][5] = bhi.y; acc[j][6] = bhi.z; acc[j][7] = bhi.w;
        }
    }
    for (int k = 0; k < 256; k++) {
        const float4* wrow = reinterpret_cast<const float4*>(Wp + (size_t)k * AS);
        float4 wlo = wrow[2 * t], whi = wrow[2 * t + 1];
        float w[8];
        w[0] = wlo.x; w[1] = wlo.y; w[2] = wlo.z; w[3] = wlo.w;
        w[4] = whi.x; w[5] = whi.y; w[6] = whi.z; w[7] = whi.w;
#pragma unroll
        for (int j = 0; j < 8; j++) {
            float bv = lds[j][k];
#pragma unroll
            for (int c = 0; c < 8; c++) acc[j][c] += bv * w[c];
        }
    }
    for (int j = 0; j < 8; j++) {
        float sq = 0.f;
#pragma unroll
        for (int c = 0; c < 8; c++) sq += acc[j][c] * acc[j][c];
#pragma unroll
        for (int d = 32; d > 0; d >>= 1) sq += __shfl_xor(sq, d, 64);
        if ((t & 63) == 0) red[t >> 6] = sq;
        __syncthreads();
        float norm = sqrtf(red[0] + red[1] + red[2] + red[3]);
        float r = 1.0f / fmaxf(norm, 1e-12f);
        if ((t >> 3) == g) {
            int local = (t - 8 * g) * 8;  // col 8t+c -> local 8(t-8g)+c
#pragma unroll
            for (int c = 0; c < 8; c++)
                raws[(size_t)(base + j) * KC + local + c] = fmaxf(acc[j][c] * r, 0.0f);
        }
        __syncthreads();
    }
}

// ---------------- per-node softmax over 64 in-graph clusters ----------------
__global__ void softmax_kernel(const float* __restrict__ raws, float* __restrict__ s) {
    int n = blockIdx.x;
    int t = threadIdx.x;  // 64
    float v = raws[(size_t)n * KC + t];
    float m = v;
#pragma unroll
    for (int d = 32; d > 0; d >>= 1) m = fmaxf(m, __shfl_xor(m, d, 64));
    float e = __expf(v - m);
    float z = e;
#pragma unroll
    for (int d = 32; d > 0; d >>= 1) z += __shfl_xor(z, d, 64);
    s[(size_t)n * KC + t] = e / z;
}

// ---------------- a_s = segment_sum(s[src], dst), compact cols ----------------
__global__ void agg_s_kernel(const float* __restrict__ s, const int* __restrict__ off,
                             const int* __restrict__ csr, float* __restrict__ as_) {
    int n = blockIdx.x;
    int t = threadIdx.x;  // 64
    int b0 = off[n], b1 = off[n + 1];
    float a = 0.f;
    for (int i = b0; i < b1; i++) a += s[(size_t)csr[i] * KC + t];
    as_[(size_t)n * KC + t] = a;
}

// ---------------- h_new = s^T feat, per-graph [64x128] ----------------
__global__ void hnew_kernel(const float* __restrict__ s, const float* __restrict__ feat,
                            float* __restrict__ hnewf) {
    int g = blockIdx.y, ch = blockIdx.x;  // 4 chunks of 128 nodes
    int t = threadIdx.x;                  // 256
    __shared__ float s_sub[32][64];
    __shared__ float f_sub[32][128];
    int col = t & 127, half = t >> 7;
    float acc[32];
#pragma unroll
    for (int i = 0; i < 32; i++) acc[i] = 0.f;
    int nbase0 = g * NPER + ch * 128;
    for (int sub = 0; sub < 4; sub++) {
        int nbase = nbase0 + sub * 32;
        for (int q = 0; q < 8; q++) {
            int idx = t + 256 * q;
            ((float*)s_sub)[idx] = s[(size_t)nbase * KC + idx];
        }
        for (int q = 0; q < 16; q++) {
            int idx = t + 256 * q;
            ((float*)f_sub)[idx] = feat[(size_t)nbase * DD + idx];
        }
        __syncthreads();
        for (int nd = 0; nd < 32; nd++) {
            float f = f_sub[nd][col];
#pragma unroll
            for (int i = 0; i < 32; i++) acc[i] += s_sub[nd][half + 2 * i] * f;
        }
        __syncthreads();
    }
    for (int i = 0; i < 32; i++) {
        int c = half + 2 * i;
        atomicAdd(&hnewf[(size_t)(g * KC + c) * DD + col], acc[i]);
    }
}

// ---------------- adj diag blocks: s^T a_s, per-graph [64x64] ----------------
__global__ void adj_kernel(const float* __restrict__ s, const float* __restrict__ as_,
                           float* __restrict__ adjf) {
    int g = blockIdx.y, ch = blockIdx.x;  // 4 chunks of 128 nodes
    int t = threadIdx.x;                  // 256
    __shared__ float s1[64][64];
    __shared__ float a2[64][64];
    int c2 = t & 63, q = t >> 6;
    float acc[16];
#pragma unroll
    for (int i = 0; i < 16; i++) acc[i] = 0.f;
    int nbase0 = g * NPER + ch * 128;
    for (int sub = 0; sub < 2; sub++) {
        int nbase = nbase0 + sub * 64;
        for (int qq = 0; qq < 16; qq++) {
            int idx = t + 256 * qq;
            ((float*)s1)[idx] = s[(size_t)nbase * KC + idx];
            ((float*)a2)[idx] = as_[(size_t)nbase * KC + idx];
        }
        __syncthreads();
        for (int nd = 0; nd < 64; nd++) {
            float av = a2[nd][c2];
#pragma unroll
            for (int i = 0; i < 16; i++) acc[i] += s1[nd][q + 4 * i] * av;
        }
        __syncthreads();
    }
    for (int i = 0; i < 16; i++) {
        int c1 = q + 4 * i;
        atomicAdd(&adjf[(size_t)(g * KC + c1) * AS + g * KC + c2], acc[i]);
    }
}

extern "C" void kernel_launch(void* const* d_in, const int* in_sizes, int n_in,
                              void* d_out, int out_size, void* d_ws, size_t ws_size,
                              hipStream_t stream) {
    const float* h   = (const float*)d_in[0];
    const float* Wf  = (const float*)d_in[1];
    const float* bfe = (const float*)d_in[2];
    const float* Wp  = (const float*)d_in[3];
    const float* bp  = (const float*)d_in[4];
    const int* esrc  = (const int*)d_in[5];
    const int* edst  = (const int*)d_in[6];

    // outputs accumulate directly into d_out (fp32): [adj 2048x2048][h_new 2048x128]
    float* adjf  = (float*)d_out;
    float* hnewf = adjf + (size_t)AS * AS;

    float* wsf   = (float*)d_ws;
    float* hn    = wsf;                          // NN*DD
    float* feat  = hn + (size_t)NN * DD;         // NN*DD
    float* raws  = feat + (size_t)NN * DD;       // NN*KC
    float* sArr  = raws + (size_t)NN * KC;       // NN*KC
    float* asArr = sArr + (size_t)NN * KC;       // NN*KC
    int* cnt     = (int*)(asArr + (size_t)NN * KC);
    int* off     = cnt + NN;
    int* cursor  = off + NN + 1;
    int* csr     = cursor + NN;

    hipMemsetAsync(cnt, 0, NN * sizeof(int), stream);
    hipMemsetAsync(d_out, 0, ((size_t)AS * AS + (size_t)AS * DD) * sizeof(float), stream);

    count_kernel<<<EE / 256, 256, 0, stream>>>(edst, cnt);
    scan_kernel<<<1, 256, 0, stream>>>(cnt, off, cursor);
    scatter_kernel<<<EE / 256, 256, 0, stream>>>(esrc, edst, cursor, csr);
    agg_h_kernel<<<NN, 128, 0, stream>>>(h, off, csr, hn);
    feat_kernel<<<NN / 8, 128, 0, stream>>>(h, hn, Wf, bfe, feat);
    pool_kernel<<<NN / 8, 256, 0, stream>>>(h, hn, Wp, bp, raws);
    softmax_kernel<<<NN, 64, 0, stream>>>(raws, sArr);
    agg_s_kernel<<<NN, 64, 0, stream>>>(sArr, off, csr, asArr);
    hnew_kernel<<<dim3(4, NB), 256, 0, stream>>>(sArr, feat, hnewf);
    adj_kernel<<<dim3(4, NB), 256, 0, stream>>>(sArr, asArr, adjf);
}

// Round 3
// 255.904 us; speedup vs baseline: 1.7204x; 1.7204x over previous
//
#include <hip/hip_runtime.h>

#define NB   32      // graphs
#define NPER 512     // nodes per graph
#define NN   16384   // total nodes
#define EE   262144  // edges
#define DD   128     // D_IN == D_OUT
#define AS   2048    // total clusters
#define KC   64      // clusters per graph

using short8  = __attribute__((ext_vector_type(8))) short;   // 8 bf16 (4 VGPRs)
using floatx4 = __attribute__((ext_vector_type(4))) float;   // MFMA acc
using ushort4v = __attribute__((ext_vector_type(4))) unsigned short;

// float -> bf16 bits, round-to-nearest-even
static __device__ __forceinline__ unsigned short f2b(float x) {
    union { float f; unsigned int u; } v; v.f = x;
    unsigned int r = v.u + 0x7fffu + ((v.u >> 16) & 1u);
    return (unsigned short)(r >> 16);
}

// ---------------- CSR build ----------------
__global__ void count_kernel(const int* __restrict__ edst, int* __restrict__ cnt) {
    int e = blockIdx.x * 256 + threadIdx.x;
    atomicAdd(&cnt[edst[e]], 1);
}

__global__ void scan_kernel(const int* __restrict__ cnt, int* __restrict__ off,
                            int* __restrict__ cursor) {
    __shared__ int sums[256];
    int t = threadIdx.x;
    int base = t * 64;
    int sum = 0;
    for (int i = 0; i < 64; i++) sum += cnt[base + i];
    sums[t] = sum;
    __syncthreads();
    for (int d = 1; d < 256; d <<= 1) {
        int add = (t >= d) ? sums[t - d] : 0;
        __syncthreads();
        sums[t] += add;
        __syncthreads();
    }
    int run = (t == 0) ? 0 : sums[t - 1];
    for (int i = 0; i < 64; i++) {
        off[base + i] = run;
        cursor[base + i] = run;
        run += cnt[base + i];
    }
    if (t == 255) off[NN] = run;
}

__global__ void scatter_kernel(const int* __restrict__ esrc, const int* __restrict__ edst,
                               int* __restrict__ cursor, int* __restrict__ csr) {
    int e = blockIdx.x * 256 + threadIdx.x;
    int p = atomicAdd(&cursor[edst[e]], 1);
    csr[p] = esrc[e];
}

// ---------------- bundle build: cols 0-127 = bf16(h) ----------------
__global__ void cast_h_kernel(const float* __restrict__ h, unsigned short* __restrict__ bundle) {
    int gid = blockIdx.x * 256 + threadIdx.x;        // one float4 each
    float4 v = reinterpret_cast<const float4*>(h)[gid];
    int f = gid << 2;
    int n = f >> 7, c = f & 127;
    ushort4v o = { f2b(v.x), f2b(v.y), f2b(v.z), f2b(v.w) };
    *reinterpret_cast<ushort4v*>(&bundle[(size_t)n * 256 + c]) = o;
}

// ---------------- neighbor mean -> bundle cols 128-255 (bf16) ----------------
__global__ void agg_h_kernel(const float* __restrict__ h, const int* __restrict__ off,
                             const int* __restrict__ csr, unsigned short* __restrict__ bundle) {
    int n = blockIdx.x;
    int t = threadIdx.x;  // 128
    int b0 = off[n], b1 = off[n + 1];
    float a = 0.f;
    for (int i = b0; i < b1; i++) a += h[(size_t)csr[i] * DD + t];
    float deg = fmaxf((float)(b1 - b0), 1.0f);
    bundle[(size_t)n * 256 + 128 + t] = f2b(a / deg);
}

// ---------------- transpose + cast: in fp32 [R][C] -> out bf16 [C][R] ----------------
__global__ void transpose_cast_kernel(const float* __restrict__ in, unsigned short* __restrict__ out,
                                      int R, int C) {
    __shared__ float tl[32][33];
    int tx = threadIdx.x, ty = threadIdx.y;  // (32, 8)
    int c0 = blockIdx.x * 32, r0 = blockIdx.y * 32;
    for (int i = 0; i < 4; i++)
        tl[ty + 8 * i][tx] = in[(size_t)(r0 + ty + 8 * i) * C + c0 + tx];
    __syncthreads();
    for (int i = 0; i < 4; i++)
        out[(size_t)(c0 + ty + 8 * i) * R + r0 + tx] = f2b(tl[tx][ty + 8 * i]);
}

// ---------------- K-chunk staging: [nrows][32] bf16 slab into LDS ----------------
static __device__ __forceinline__ void stage(const unsigned short* __restrict__ g, int row0,
                                             int k0, unsigned short* l, int nrows, int tid) {
    int nt = nrows * 4;  // 16B units
    for (int t = tid; t < nt; t += 256) {
        int row = t >> 2, kk = (t & 3) << 3;
        const uint4* src = reinterpret_cast<const uint4*>(g + (size_t)(row0 + row) * 256 + k0 + kk);
        *reinterpret_cast<uint4*>(l + 8 * t) = *src;
    }
}

// ---------------- feat GEMM (MFMA) + bias + L2norm + relu ----------------
__global__ __launch_bounds__(256) void feat_mfma_kernel(const unsigned short* __restrict__ bundle,
    const unsigned short* __restrict__ WfT, const float* __restrict__ bfe,
    float* __restrict__ feat) {
    __shared__ unsigned short lA[64 * 32];
    __shared__ unsigned short lB[128 * 32];
    int tid = threadIdx.x;
    int r0 = blockIdx.x * 64;
    int wv = tid >> 6, lane = tid & 63, q = lane >> 4, lm = lane & 15;
    floatx4 acc[8];
#pragma unroll
    for (int nt = 0; nt < 8; nt++) acc[nt] = (floatx4)0.f;
    for (int k0 = 0; k0 < 256; k0 += 32) {
        stage(bundle, r0, k0, lA, 64, tid);
        stage(WfT, 0, k0, lB, 128, tid);
        __syncthreads();
        short8 aF = *reinterpret_cast<const short8*>(&lA[(32 * (wv >> 1) * 0 + 16 * wv + lm) * 32 + 8 * q]);
#pragma unroll
        for (int nt = 0; nt < 8; nt++) {
            short8 bF = *reinterpret_cast<const short8*>(&lB[(16 * nt + lm) * 32 + 8 * q]);
            acc[nt] = __builtin_amdgcn_mfma_f32_16x16x32_bf16(aF, bF, acc[nt], 0, 0, 0);
        }
        __syncthreads();
    }
#pragma unroll
    for (int nt = 0; nt < 8; nt++) {
        float bv = bfe[16 * nt + lm];
#pragma unroll
        for (int r = 0; r < 4; r++) acc[nt][r] += bv;
    }
#pragma unroll
    for (int r = 0; r < 4; r++) {
        float p = 0.f;
#pragma unroll
        for (int nt = 0; nt < 8; nt++) p += acc[nt][r] * acc[nt][r];
        p += __shfl_xor(p, 1, 64);
        p += __shfl_xor(p, 2, 64);
        p += __shfl_xor(p, 4, 64);
        p += __shfl_xor(p, 8, 64);
        float rn = 1.0f / fmaxf(sqrtf(p), 1e-12f);
        int row = r0 + 16 * wv + 4 * q + r;
#pragma unroll
        for (int nt = 0; nt < 8; nt++)
            feat[(size_t)row * DD + 16 * nt + lm] = fmaxf(acc[nt][r] * rn, 0.f);
    }
}

// ---------------- pool GEMM (MFMA): bias + ssq partials + in-graph raw cols ----------------
__global__ __launch_bounds__(256) void pool_mfma_kernel(const unsigned short* __restrict__ bundle,
    const unsigned short* __restrict__ WpT, const float* __restrict__ bp,
    float* __restrict__ ssq, float* __restrict__ sraw) {
    __shared__ unsigned short lA[64 * 32];
    __shared__ unsigned short lB[128 * 32];
    int tid = threadIdx.x;
    int r0 = blockIdx.x * 64, c0 = blockIdx.y * 128;
    int wv = tid >> 6, lane = tid & 63;
    int mw = wv >> 1, nw = wv & 1, q = lane >> 4, lm = lane & 15;
    floatx4 acc[2][4];
#pragma unroll
    for (int mt = 0; mt < 2; mt++)
#pragma unroll
        for (int nt = 0; nt < 4; nt++) acc[mt][nt] = (floatx4)0.f;
    for (int k0 = 0; k0 < 256; k0 += 32) {
        stage(bundle, r0, k0, lA, 64, tid);
        stage(WpT, c0, k0, lB, 128, tid);
        __syncthreads();
        short8 aF[2], bF[4];
#pragma unroll
        for (int mt = 0; mt < 2; mt++)
            aF[mt] = *reinterpret_cast<const short8*>(&lA[(32 * mw + 16 * mt + lm) * 32 + 8 * q]);
#pragma unroll
        for (int nt = 0; nt < 4; nt++)
            bF[nt] = *reinterpret_cast<const short8*>(&lB[(64 * nw + 16 * nt + lm) * 32 + 8 * q]);
#pragma unroll
        for (int mt = 0; mt < 2; mt++)
#pragma unroll
            for (int nt = 0; nt < 4; nt++)
                acc[mt][nt] = __builtin_amdgcn_mfma_f32_16x16x32_bf16(aF[mt], bF[nt], acc[mt][nt], 0, 0, 0);
        __syncthreads();
    }
    // bias
#pragma unroll
    for (int nt = 0; nt < 4; nt++) {
        float bv = bp[c0 + 64 * nw + 16 * nt + lm];
#pragma unroll
        for (int mt = 0; mt < 2; mt++)
#pragma unroll
            for (int r = 0; r < 4; r++) acc[mt][nt][r] += bv;
    }
    // per-row sum-of-squares partial (this wave's 64 cols), butterfly over 16 lanes
#pragma unroll
    for (int mt = 0; mt < 2; mt++)
#pragma unroll
        for (int r = 0; r < 4; r++) {
            float p = 0.f;
#pragma unroll
            for (int nt = 0; nt < 4; nt++) p += acc[mt][nt][r] * acc[mt][nt][r];
            p += __shfl_xor(p, 1, 64);
            p += __shfl_xor(p, 2, 64);
            p += __shfl_xor(p, 4, 64);
            p += __shfl_xor(p, 8, 64);
            if (lm == 0) atomicAdd(&ssq[r0 + 32 * mw + 16 * mt + 4 * q + r], p);
        }
    // in-graph raw columns -> compact [row][64]
    int g = r0 >> 9;                      // graph id (64 rows all in one graph)
    if ((int)blockIdx.y == (g >> 1) && nw == (g & 1)) {
#pragma unroll
        for (int mt = 0; mt < 2; mt++)
#pragma unroll
            for (int nt = 0; nt < 4; nt++)
#pragma unroll
                for (int r = 0; r < 4; r++)
                    sraw[(size_t)(r0 + 32 * mw + 16 * mt + 4 * q + r) * KC + 16 * nt + lm] =
                        acc[mt][nt][r];
    }
}

// ---------------- norm + relu + softmax over 64 in-graph clusters (in place) ----------------
__global__ void softmax_kernel(const float* __restrict__ ssq, float* __restrict__ s) {
    int n = blockIdx.x;
    int t = threadIdx.x;  // 64
    float rn = 1.0f / fmaxf(sqrtf(ssq[n]), 1e-12f);
    float v = fmaxf(s[(size_t)n * KC + t] * rn, 0.f);
    float m = v;
#pragma unroll
    for (int d = 32; d > 0; d >>= 1) m = fmaxf(m, __shfl_xor(m, d, 64));
    float e = __expf(v - m);
    float z = e;
#pragma unroll
    for (int d = 32; d > 0; d >>= 1) z += __shfl_xor(z, d, 64);
    s[(size_t)n * KC + t] = e / z;
}

// ---------------- a_s = segment_sum(s[src], dst), compact cols ----------------
__global__ void agg_s_kernel(const float* __restrict__ s, const int* __restrict__ off,
                             const int* __restrict__ csr, float* __restrict__ as_) {
    int n = blockIdx.x;
    int t = threadIdx.x;  // 64
    int b0 = off[n], b1 = off[n + 1];
    float a = 0.f;
    for (int i = b0; i < b1; i++) a += s[(size_t)csr[i] * KC + t];
    as_[(size_t)n * KC + t] = a;
}

// ---------------- h_new = s^T feat, per-graph [64x128] ----------------
__global__ void hnew_kernel(const float* __restrict__ s, const float* __restrict__ feat,
                            float* __restrict__ hnewf) {
    int g = blockIdx.y, ch = blockIdx.x;  // 4 chunks of 128 nodes
    int t = threadIdx.x;                  // 256
    __shared__ float s_sub[32][64];
    __shared__ float f_sub[32][128];
    int col = t & 127, half = t >> 7;
    float acc[32];
#pragma unroll
    for (int i = 0; i < 32; i++) acc[i] = 0.f;
    int nbase0 = g * NPER + ch * 128;
    for (int sub = 0; sub < 4; sub++) {
        int nbase = nbase0 + sub * 32;
        for (int q = 0; q < 8; q++) {
            int idx = t + 256 * q;
            ((float*)s_sub)[idx] = s[(size_t)nbase * KC + idx];
        }
        for (int q = 0; q < 16; q++) {
            int idx = t + 256 * q;
            ((float*)f_sub)[idx] = feat[(size_t)nbase * DD + idx];
        }
        __syncthreads();
        for (int nd = 0; nd < 32; nd++) {
            float f = f_sub[nd][col];
#pragma unroll
            for (int i = 0; i < 32; i++) acc[i] += s_sub[nd][half + 2 * i] * f;
        }
        __syncthreads();
    }
    for (int i = 0; i < 32; i++) {
        int c = half + 2 * i;
        atomicAdd(&hnewf[(size_t)(g * KC + c) * DD + col], acc[i]);
    }
}

// ---------------- adj diag blocks: s^T a_s, per-graph [64x64] ----------------
__global__ void adj_kernel(const float* __restrict__ s, const float* __restrict__ as_,
                           float* __restrict__ adjf) {
    int g = blockIdx.y, ch = blockIdx.x;  // 4 chunks of 128 nodes
    int t = threadIdx.x;                  // 256
    __shared__ float s1[64][64];
    __shared__ float a2[64][64];
    int c2 = t & 63, q = t >> 6;
    float acc[16];
#pragma unroll
    for (int i = 0; i < 16; i++) acc[i] = 0.f;
    int nbase0 = g * NPER + ch * 128;
    for (int sub = 0; sub < 2; sub++) {
        int nbase = nbase0 + sub * 64;
        for (int qq = 0; qq < 16; qq++) {
            int idx = t + 256 * qq;
            ((float*)s1)[idx] = s[(size_t)nbase * KC + idx];
            ((float*)a2)[idx] = as_[(size_t)nbase * KC + idx];
        }
        __syncthreads();
        for (int nd = 0; nd < 64; nd++) {
            float av = a2[nd][c2];
#pragma unroll
            for (int i = 0; i < 16; i++) acc[i] += s1[nd][q + 4 * i] * av;
        }
        __syncthreads();
    }
    for (int i = 0; i < 16; i++) {
        int c1 = q + 4 * i;
        atomicAdd(&adjf[(size_t)(g * KC + c1) * AS + g * KC + c2], acc[i]);
    }
}

extern "C" void kernel_launch(void* const* d_in, const int* in_sizes, int n_in,
                              void* d_out, int out_size, void* d_ws, size_t ws_size,
                              hipStream_t stream) {
    const float* h   = (const float*)d_in[0];
    const float* Wf  = (const float*)d_in[1];
    const float* bfe = (const float*)d_in[2];
    const float* Wp  = (const float*)d_in[3];
    const float* bp  = (const float*)d_in[4];
    const int* esrc  = (const int*)d_in[5];
    const int* edst  = (const int*)d_in[6];

    // outputs accumulate directly into d_out (fp32): [adj 2048x2048][h_new 2048x128]
    float* adjf  = (float*)d_out;
    float* hnewf = adjf + (size_t)AS * AS;

    float* wsf = (float*)d_ws;
    float* ssq   = wsf;                               // NN
    float* sArr  = ssq + NN;                          // NN*KC (raw -> s in place)
    float* asArr = sArr + (size_t)NN * KC;            // NN*KC
    float* feat  = asArr + (size_t)NN * KC;           // NN*DD
    unsigned short* bundle = (unsigned short*)(feat + (size_t)NN * DD);  // NN*256 bf16
    unsigned short* WfT = bundle + (size_t)NN * 256;  // 128*256 bf16
    unsigned short* WpT = WfT + 128 * 256;            // 2048*256 bf16
    int* cnt    = (int*)(WpT + (size_t)AS * 256);
    int* off    = cnt + NN;
    int* cursor = off + NN + 1;
    int* csr    = cursor + NN;

    hipMemsetAsync(cnt, 0, NN * sizeof(int), stream);
    hipMemsetAsync(ssq, 0, NN * sizeof(float), stream);
    hipMemsetAsync(d_out, 0, ((size_t)AS * AS + (size_t)AS * DD) * sizeof(float), stream);

    count_kernel<<<EE / 256, 256, 0, stream>>>(edst, cnt);
    scan_kernel<<<1, 256, 0, stream>>>(cnt, off, cursor);
    scatter_kernel<<<EE / 256, 256, 0, stream>>>(esrc, edst, cursor, csr);

    cast_h_kernel<<<NN * DD / 4 / 256, 256, 0, stream>>>(h, bundle);
    agg_h_kernel<<<NN, 128, 0, stream>>>(h, off, csr, bundle);

    transpose_cast_kernel<<<dim3(DD / 32, 256 / 32), dim3(32, 8), 0, stream>>>(Wf, WfT, 256, DD);
    transpose_cast_kernel<<<dim3(AS / 32, 256 / 32), dim3(32, 8), 0, stream>>>(Wp, WpT, 256, AS);

    feat_mfma_kernel<<<NN / 64, 256, 0, stream>>>(bundle, WfT, bfe, feat);
    pool_mfma_kernel<<<dim3(NN / 64, AS / 128), 256, 0, stream>>>(bundle, WpT, bp, ssq, sArr);

    softmax_kernel<<<NN, 64, 0, stream>>>(ssq, sArr);
    agg_s_kernel<<<NN, 64, 0, stream>>>(sArr, off, csr, asArr);
    hnew_kernel<<<dim3(4, NB), 256, 0, stream>>>(sArr, feat, hnewf);
    adj_kernel<<<dim3(4, NB), 256, 0, stream>>>(sArr, asArr, adjf);
}

// Round 4
// 233.273 us; speedup vs baseline: 1.8873x; 1.0970x over previous
//
#include <hip/hip_runtime.h>

#define NB   32      // graphs
#define NPER 512     // nodes per graph
#define NN   16384   // total nodes
#define EE   262144  // edges
#define DD   128     // D_IN == D_OUT
#define AS   2048    // total clusters
#define KC   64      // clusters per graph

using short8   = __attribute__((ext_vector_type(8))) short;   // 8 bf16 (4 VGPRs)
using floatx4  = __attribute__((ext_vector_type(4))) float;   // MFMA acc
using ushort4v = __attribute__((ext_vector_type(4))) unsigned short;

typedef __attribute__((address_space(3))) unsigned int lds_u32;
typedef const __attribute__((address_space(1))) unsigned int gbl_u32;

// async 16B global -> LDS (wave-uniform base + lane*16 semantics; layout linear in tid)
static __device__ __forceinline__ void gload16(const unsigned short* g, unsigned short* l) {
    __builtin_amdgcn_global_load_lds((gbl_u32*)g, (lds_u32*)l, 16, 0, 0);
}

// float -> bf16 bits, round-to-nearest-even
static __device__ __forceinline__ unsigned short f2b(float x) {
    union { float f; unsigned int u; } v; v.f = x;
    unsigned int r = v.u + 0x7fffu + ((v.u >> 16) & 1u);
    return (unsigned short)(r >> 16);
}

// ---------------- CSR build ----------------
__global__ void count_kernel(const int* __restrict__ edst, int* __restrict__ cnt) {
    int e = blockIdx.x * 256 + threadIdx.x;
    atomicAdd(&cnt[edst[e]], 1);
}

__global__ void scan_kernel(const int* __restrict__ cnt, int* __restrict__ off,
                            int* __restrict__ cursor) {
    __shared__ int sums[256];
    int t = threadIdx.x;
    int base = t * 64;
    int sum = 0;
    for (int i = 0; i < 64; i++) sum += cnt[base + i];
    sums[t] = sum;
    __syncthreads();
    for (int d = 1; d < 256; d <<= 1) {
        int add = (t >= d) ? sums[t - d] : 0;
        __syncthreads();
        sums[t] += add;
        __syncthreads();
    }
    int run = (t == 0) ? 0 : sums[t - 1];
    for (int i = 0; i < 64; i++) {
        off[base + i] = run;
        cursor[base + i] = run;
        run += cnt[base + i];
    }
    if (t == 255) off[NN] = run;
}

__global__ void scatter_kernel(const int* __restrict__ esrc, const int* __restrict__ edst,
                               int* __restrict__ cursor, int* __restrict__ csr) {
    int e = blockIdx.x * 256 + threadIdx.x;
    int p = atomicAdd(&cursor[edst[e]], 1);
    csr[p] = esrc[e];
}

// ---------------- bundle build: cols 0-127 = bf16(h) ----------------
__global__ void cast_h_kernel(const float* __restrict__ h, unsigned short* __restrict__ bundle) {
    int gid = blockIdx.x * 256 + threadIdx.x;        // one float4 each
    float4 v = reinterpret_cast<const float4*>(h)[gid];
    int f = gid << 2;
    int n = f >> 7, c = f & 127;
    ushort4v o = { f2b(v.x), f2b(v.y), f2b(v.z), f2b(v.w) };
    *reinterpret_cast<ushort4v*>(&bundle[(size_t)n * 256 + c]) = o;
}

// ---------------- neighbor mean -> bundle cols 128-255 (bf16), float4 gather ----------
__global__ void agg_h_kernel(const float* __restrict__ h, const int* __restrict__ off,
                             const int* __restrict__ csr, unsigned short* __restrict__ bundle) {
    int t = threadIdx.x;                 // 256 = 8 nodes x 32 lanes
    int n = blockIdx.x * 8 + (t >> 5);
    int l = t & 31;
    const float4* h4 = reinterpret_cast<const float4*>(h);
    int b0 = off[n], b1 = off[n + 1];
    float4 a = {0.f, 0.f, 0.f, 0.f};
    for (int i = b0; i < b1; i++) {
        int s = csr[i];
        float4 v = h4[(size_t)s * 32 + l];
        a.x += v.x; a.y += v.y; a.z += v.z; a.w += v.w;
    }
    float inv = 1.0f / fmaxf((float)(b1 - b0), 1.0f);
    ushort4v o = { f2b(a.x * inv), f2b(a.y * inv), f2b(a.z * inv), f2b(a.w * inv) };
    *reinterpret_cast<ushort4v*>(&bundle[(size_t)n * 256 + 128 + 4 * l]) = o;
}

// ------------- transpose + cast both weights: fp32 [256][C] -> bf16 [C][256] -------------
__global__ void transpose_cast2_kernel(const float* __restrict__ Wf, const float* __restrict__ Wp,
                                       unsigned short* __restrict__ WfT, unsigned short* __restrict__ WpT) {
    __shared__ float tl[32][33];
    int tx = threadIdx.x, ty = threadIdx.y;  // (32, 8)
    int bx = blockIdx.x;
    const float* in; unsigned short* out; int C, cb;
    if (bx < DD / 32) { in = Wf; out = WfT; C = DD; cb = bx; }
    else              { in = Wp; out = WpT; C = AS; cb = bx - DD / 32; }
    int c0 = cb * 32, r0 = blockIdx.y * 32;
    for (int i = 0; i < 4; i++)
        tl[ty + 8 * i][tx] = in[(size_t)(r0 + ty + 8 * i) * C + c0 + tx];
    __syncthreads();
    for (int i = 0; i < 4; i++)
        out[(size_t)(c0 + ty + 8 * i) * 256 + r0 + tx] = f2b(tl[tx][ty + 8 * i]);
}

// ---------------- fused GEMM (m97-style): by<16 -> pool cols, by==16 -> feat ----------------
// block tile 128x128, 4 waves each 64x64 (4x4 frags of 16x16x32 bf16).
// LDS layout [row][32 shorts], K-chunks XOR-swizzled: chunk' = q ^ (row&3).
__global__ __launch_bounds__(256) void gemm_kernel(
    const unsigned short* __restrict__ bundle, const unsigned short* __restrict__ WfT,
    const unsigned short* __restrict__ WpT, const float* __restrict__ bfe,
    const float* __restrict__ bp, float* __restrict__ feat,
    float* __restrict__ ssq, float* __restrict__ sraw) {
    __shared__ alignas(16) unsigned short lA[128 * 32];
    __shared__ alignas(16) unsigned short lB[128 * 32];
    __shared__ float red[256];
    int tid = threadIdx.x;
    int bx = blockIdx.x, by = blockIdx.y;
    bool isFeat = (by == 16);
    const unsigned short* B = isFeat ? WfT : WpT;
    int r0 = bx * 128;
    int c0 = isFeat ? 0 : by * 128;
    int wv = tid >> 6, lane = tid & 63;
    int mw = wv >> 1, nw = wv & 1, q = lane >> 4, lm = lane & 15;
    int kq = 8 * (q ^ (lm & 3));   // swizzled K-chunk offset for frag reads
    // staging decode for this thread's two 16B units per matrix
    int ur0 = tid >> 2,           uc0 = 8 * ((tid & 3) ^ (ur0 & 3));
    int ur1 = (tid + 256) >> 2,   uc1 = 8 * (((tid + 256) & 3) ^ (ur1 & 3));

    floatx4 acc[4][4];
#pragma unroll
    for (int mi = 0; mi < 4; mi++)
#pragma unroll
        for (int ni = 0; ni < 4; ni++) acc[mi][ni] = (floatx4)0.f;

    for (int k0 = 0; k0 < 256; k0 += 32) {
        gload16(bundle + (size_t)(r0 + ur0) * 256 + k0 + uc0, &lA[tid * 8]);
        gload16(bundle + (size_t)(r0 + ur1) * 256 + k0 + uc1, &lA[(tid + 256) * 8]);
        gload16(B + (size_t)(c0 + ur0) * 256 + k0 + uc0, &lB[tid * 8]);
        gload16(B + (size_t)(c0 + ur1) * 256 + k0 + uc1, &lB[(tid + 256) * 8]);
        __syncthreads();
        short8 aF[4], bF[4];
#pragma unroll
        for (int mi = 0; mi < 4; mi++)
            aF[mi] = *reinterpret_cast<const short8*>(&lA[(64 * mw + 16 * mi + lm) * 32 + kq]);
#pragma unroll
        for (int ni = 0; ni < 4; ni++)
            bF[ni] = *reinterpret_cast<const short8*>(&lB[(64 * nw + 16 * ni + lm) * 32 + kq]);
#pragma unroll
        for (int mi = 0; mi < 4; mi++)
#pragma unroll
            for (int ni = 0; ni < 4; ni++)
                acc[mi][ni] = __builtin_amdgcn_mfma_f32_16x16x32_bf16(aF[mi], bF[ni], acc[mi][ni], 0, 0, 0);
        __syncthreads();
    }

    if (isFeat) {
        // bias, block-local L2 norm (all 128 cols in this block), relu, store feat
#pragma unroll
        for (int ni = 0; ni < 4; ni++) {
            float bv = bfe[64 * nw + 16 * ni + lm];
#pragma unroll
            for (int mi = 0; mi < 4; mi++)
#pragma unroll
                for (int r = 0; r < 4; r++) acc[mi][ni][r] += bv;
        }
#pragma unroll
        for (int mi = 0; mi < 4; mi++)
#pragma unroll
            for (int r = 0; r < 4; r++) {
                float p = 0.f;
#pragma unroll
                for (int ni = 0; ni < 4; ni++) p += acc[mi][ni][r] * acc[mi][ni][r];
                p += __shfl_xor(p, 1, 64);
                p += __shfl_xor(p, 2, 64);
                p += __shfl_xor(p, 4, 64);
                p += __shfl_xor(p, 8, 64);
                if (lm == 0) red[nw * 128 + 64 * mw + 16 * mi + 4 * q + r] = p;
            }
        __syncthreads();
#pragma unroll
        for (int mi = 0; mi < 4; mi++)
#pragma unroll
            for (int r = 0; r < 4; r++) {
                int rl = 64 * mw + 16 * mi + 4 * q + r;
                float rn = 1.0f / fmaxf(sqrtf(red[rl] + red[128 + rl]), 1e-12f);
                int row = r0 + rl;
#pragma unroll
                for (int ni = 0; ni < 4; ni++)
                    feat[(size_t)row * DD + 64 * nw + 16 * ni + lm] =
                        fmaxf(acc[mi][ni][r] * rn, 0.f);
            }
    } else {
        // bias, ssq partials (atomic), in-graph raw col extraction
#pragma unroll
        for (int ni = 0; ni < 4; ni++) {
            float bv = bp[c0 + 64 * nw + 16 * ni + lm];
#pragma unroll
            for (int mi = 0; mi < 4; mi++)
#pragma unroll
                for (int r = 0; r < 4; r++) acc[mi][ni][r] += bv;
        }
#pragma unroll
        for (int mi = 0; mi < 4; mi++)
#pragma unroll
            for (int r = 0; r < 4; r++) {
                float p = 0.f;
#pragma unroll
                for (int ni = 0; ni < 4; ni++) p += acc[mi][ni][r] * acc[mi][ni][r];
                p += __shfl_xor(p, 1, 64);
                p += __shfl_xor(p, 2, 64);
                p += __shfl_xor(p, 4, 64);
                p += __shfl_xor(p, 8, 64);
                if (lm == 0) atomicAdd(&ssq[r0 + 64 * mw + 16 * mi + 4 * q + r], p);
            }
        int g = bx >> 2;  // graph of these 128 rows
        if (by == (g >> 1) && nw == (g & 1)) {
#pragma unroll
            for (int mi = 0; mi < 4; mi++)
#pragma unroll
                for (int r = 0; r < 4; r++) {
                    int row = r0 + 64 * mw + 16 * mi + 4 * q + r;
#pragma unroll
                    for (int ni = 0; ni < 4; ni++)
                        sraw[(size_t)row * KC + 16 * ni + lm] = acc[mi][ni][r];
                }
        }
    }
}

// ---------------- norm + relu + softmax over 64 in-graph clusters (in place) ----------------
__global__ void softmax_kernel(const float* __restrict__ ssq, float* __restrict__ s) {
    int n = blockIdx.x;
    int t = threadIdx.x;  // 64
    float rn = 1.0f / fmaxf(sqrtf(ssq[n]), 1e-12f);
    float v = fmaxf(s[(size_t)n * KC + t] * rn, 0.f);
    float m = v;
#pragma unroll
    for (int d = 32; d > 0; d >>= 1) m = fmaxf(m, __shfl_xor(m, d, 64));
    float e = __expf(v - m);
    float z = e;
#pragma unroll
    for (int d = 32; d > 0; d >>= 1) z += __shfl_xor(z, d, 64);
    s[(size_t)n * KC + t] = e / z;
}

// ---------------- a_s = segment_sum(s[src], dst), compact cols, float4 gather ----------------
__global__ void agg_s_kernel(const float* __restrict__ s, const int* __restrict__ off,
                             const int* __restrict__ csr, float* __restrict__ as_) {
    int t = threadIdx.x;                 // 256 = 16 nodes x 16 lanes
    int n = blockIdx.x * 16 + (t >> 4);
    int l = t & 15;
    const float4* s4 = reinterpret_cast<const float4*>(s);
    int b0 = off[n], b1 = off[n + 1];
    float4 a = {0.f, 0.f, 0.f, 0.f};
    for (int i = b0; i < b1; i++) {
        float4 v = s4[(size_t)csr[i] * 16 + l];
        a.x += v.x; a.y += v.y; a.z += v.z; a.w += v.w;
    }
    reinterpret_cast<float4*>(as_)[(size_t)n * 16 + l] = a;
}

// ---------------- h_new = s^T feat, per-graph [64x128] ----------------
__global__ void hnew_kernel(const float* __restrict__ s, const float* __restrict__ feat,
                            float* __restrict__ hnewf) {
    int g = blockIdx.y, ch = blockIdx.x;  // 4 chunks of 128 nodes
    int t = threadIdx.x;                  // 256
    __shared__ float s_sub[32][64];
    __shared__ float f_sub[32][128];
    int col = t & 127, half = t >> 7;
    float acc[32];
#pragma unroll
    for (int i = 0; i < 32; i++) acc[i] = 0.f;
    int nbase0 = g * NPER + ch * 128;
    for (int sub = 0; sub < 4; sub++) {
        int nbase = nbase0 + sub * 32;
        for (int q = 0; q < 8; q++) {
            int idx = t + 256 * q;
            ((float*)s_sub)[idx] = s[(size_t)nbase * KC + idx];
        }
        for (int q = 0; q < 16; q++) {
            int idx = t + 256 * q;
            ((float*)f_sub)[idx] = feat[(size_t)nbase * DD + idx];
        }
        __syncthreads();
        for (int nd = 0; nd < 32; nd++) {
            float f = f_sub[nd][col];
#pragma unroll
            for (int i = 0; i < 32; i++) acc[i] += s_sub[nd][half + 2 * i] * f;
        }
        __syncthreads();
    }
    for (int i = 0; i < 32; i++) {
        int c = half + 2 * i;
        atomicAdd(&hnewf[(size_t)(g * KC + c) * DD + col], acc[i]);
    }
}

// ---------------- adj diag blocks: s^T a_s, per-graph [64x64] ----------------
__global__ void adj_kernel(const float* __restrict__ s, const float* __restrict__ as_,
                           float* __restrict__ adjf) {
    int g = blockIdx.y, ch = blockIdx.x;  // 4 chunks of 128 nodes
    int t = threadIdx.x;                  // 256
    __shared__ float s1[64][64];
    __shared__ float a2[64][64];
    int c2 = t & 63, q = t >> 6;
    float acc[16];
#pragma unroll
    for (int i = 0; i < 16; i++) acc[i] = 0.f;
    int nbase0 = g * NPER + ch * 128;
    for (int sub = 0; sub < 2; sub++) {
        int nbase = nbase0 + sub * 64;
        for (int qq = 0; qq < 16; qq++) {
            int idx = t + 256 * qq;
            ((float*)s1)[idx] = s[(size_t)nbase * KC + idx];
            ((float*)a2)[idx] = as_[(size_t)nbase * KC + idx];
        }
        __syncthreads();
        for (int nd = 0; nd < 64; nd++) {
            float av = a2[nd][c2];
#pragma unroll
            for (int i = 0; i < 16; i++) acc[i] += s1[nd][q + 4 * i] * av;
        }
        __syncthreads();
    }
    for (int i = 0; i < 16; i++) {
        int c1 = q + 4 * i;
        atomicAdd(&adjf[(size_t)(g * KC + c1) * AS + g * KC + c2], acc[i]);
    }
}

extern "C" void kernel_launch(void* const* d_in, const int* in_sizes, int n_in,
                              void* d_out, int out_size, void* d_ws, size_t ws_size,
                              hipStream_t stream) {
    const float* h   = (const float*)d_in[0];
    const float* Wf  = (const float*)d_in[1];
    const float* bfe = (const float*)d_in[2];
    const float* Wp  = (const float*)d_in[3];
    const float* bp  = (const float*)d_in[4];
    const int* esrc  = (const int*)d_in[5];
    const int* edst  = (const int*)d_in[6];

    // outputs accumulate directly into d_out (fp32): [adj 2048x2048][h_new 2048x128]
    float* adjf  = (float*)d_out;
    float* hnewf = adjf + (size_t)AS * AS;

    float* wsf = (float*)d_ws;
    float* ssq   = wsf;                               // NN
    float* sArr  = ssq + NN;                          // NN*KC (raw -> s in place)
    float* asArr = sArr + (size_t)NN * KC;            // NN*KC
    float* feat  = asArr + (size_t)NN * KC;           // NN*DD
    unsigned short* bundle = (unsigned short*)(feat + (size_t)NN * DD);  // NN*256 bf16
    unsigned short* WfT = bundle + (size_t)NN * 256;  // 128*256 bf16
    unsigned short* WpT = WfT + 128 * 256;            // 2048*256 bf16
    int* cnt    = (int*)(WpT + (size_t)AS * 256);
    int* off    = cnt + NN;
    int* cursor = off + NN + 1;
    int* csr    = cursor + NN;

    hipMemsetAsync(cnt, 0, NN * sizeof(int), stream);
    hipMemsetAsync(ssq, 0, NN * sizeof(float), stream);
    hipMemsetAsync(d_out, 0, ((size_t)AS * AS + (size_t)AS * DD) * sizeof(float), stream);

    count_kernel<<<EE / 256, 256, 0, stream>>>(edst, cnt);
    scan_kernel<<<1, 256, 0, stream>>>(cnt, off, cursor);
    scatter_kernel<<<EE / 256, 256, 0, stream>>>(esrc, edst, cursor, csr);

    cast_h_kernel<<<NN * DD / 4 / 256, 256, 0, stream>>>(h, bundle);
    agg_h_kernel<<<NN / 8, 256, 0, stream>>>(h, off, csr, bundle);

    transpose_cast2_kernel<<<dim3(DD / 32 + AS / 32, 256 / 32), dim3(32, 8), 0, stream>>>(
        Wf, Wp, WfT, WpT);

    gemm_kernel<<<dim3(NN / 128, 17), 256, 0, stream>>>(bundle, WfT, WpT, bfe, bp,
                                                        feat, ssq, sArr);

    softmax_kernel<<<NN, 64, 0, stream>>>(ssq, sArr);
    agg_s_kernel<<<NN / 16, 256, 0, stream>>>(sArr, off, csr, asArr);
    hnew_kernel<<<dim3(4, NB), 256, 0, stream>>>(sArr, feat, hnewf);
    adj_kernel<<<dim3(4, NB), 256, 0, stream>>>(sArr, asArr, adjf);
}

// Round 5
// 230.703 us; speedup vs baseline: 1.9083x; 1.0111x over previous
//
#include <hip/hip_runtime.h>

#define NB   32      // graphs
#define NPER 512     // nodes per graph
#define NN   16384   // total nodes
#define EE   262144  // edges
#define DD   128     // D_IN == D_OUT
#define AS   2048    // total clusters
#define KC   64      // clusters per graph

using short8   = __attribute__((ext_vector_type(8))) short;   // 8 bf16 (4 VGPRs)
using floatx4  = __attribute__((ext_vector_type(4))) float;   // MFMA acc
using ushort4v = __attribute__((ext_vector_type(4))) unsigned short;

typedef __attribute__((address_space(3))) unsigned int lds_u32;
typedef const __attribute__((address_space(1))) unsigned int gbl_u32;

// async 16B global -> LDS (wave-uniform base + lane*16; keep dest linear in tid)
static __device__ __forceinline__ void gload16(const unsigned short* g, unsigned short* l) {
    __builtin_amdgcn_global_load_lds((gbl_u32*)g, (lds_u32*)l, 16, 0, 0);
}

static __device__ __forceinline__ float bits2f(unsigned int u) {
    union { unsigned int i; float f; } z; z.i = u << 16; return z.f;
}
// float -> bf16 bits, round-to-nearest-even
static __device__ __forceinline__ unsigned short f2b(float x) {
    union { float f; unsigned int u; } v; v.f = x;
    unsigned int r = v.u + 0x7fffu + ((v.u >> 16) & 1u);
    return (unsigned short)(r >> 16);
}

// ---------------- CSR build ----------------
__global__ void count_kernel(const int* __restrict__ edst, int* __restrict__ cnt) {
    int e = blockIdx.x * 256 + threadIdx.x;
    atomicAdd(&cnt[edst[e]], 1);
}

__global__ void scan_kernel(const int* __restrict__ cnt, int* __restrict__ off,
                            int* __restrict__ cursor) {
    __shared__ int sums[256];
    int t = threadIdx.x;
    int base = t * 64;
    int sum = 0;
    for (int i = 0; i < 64; i++) sum += cnt[base + i];
    sums[t] = sum;
    __syncthreads();
    for (int d = 1; d < 256; d <<= 1) {
        int add = (t >= d) ? sums[t - d] : 0;
        __syncthreads();
        sums[t] += add;
        __syncthreads();
    }
    int run = (t == 0) ? 0 : sums[t - 1];
    for (int i = 0; i < 64; i++) {
        off[base + i] = run;
        cursor[base + i] = run;
        run += cnt[base + i];
    }
    if (t == 255) off[NN] = run;
}

__global__ void scatter_kernel(const int* __restrict__ esrc, const int* __restrict__ edst,
                               int* __restrict__ cursor, int* __restrict__ csr) {
    int e = blockIdx.x * 256 + threadIdx.x;
    int p = atomicAdd(&cursor[edst[e]], 1);
    csr[p] = esrc[e];
}

// ---------------- bundle build: cols 0-127 = bf16(h) ----------------
__global__ void cast_h_kernel(const float* __restrict__ h, unsigned short* __restrict__ bundle) {
    int gid = blockIdx.x * 256 + threadIdx.x;        // one float4 each
    float4 v = reinterpret_cast<const float4*>(h)[gid];
    int f = gid << 2;
    int n = f >> 7, c = f & 127;
    ushort4v o = { f2b(v.x), f2b(v.y), f2b(v.z), f2b(v.w) };
    *reinterpret_cast<ushort4v*>(&bundle[(size_t)n * 256 + c]) = o;
}

// ------- neighbor mean: gather bf16 lower half -> write upper half (bf16) -------
__global__ void agg_h_kernel(unsigned short* __restrict__ bundle, const int* __restrict__ off,
                             const int* __restrict__ csr) {
    int t = threadIdx.x;                 // 256 = 8 nodes x 32 lanes
    int n = blockIdx.x * 8 + (t >> 5);
    int l = t & 31;
    const uint2* b2 = reinterpret_cast<const uint2*>(bundle);  // row = 64 uint2
    int b0 = off[n], b1 = off[n + 1];
    float a0 = 0.f, a1 = 0.f, a2 = 0.f, a3 = 0.f;
    for (int i = b0; i < b1; i++) {
        int s = csr[i];
        uint2 v = b2[(size_t)s * 64 + l];
        a0 += bits2f(v.x & 0xffffu); a1 += bits2f(v.x >> 16);
        a2 += bits2f(v.y & 0xffffu); a3 += bits2f(v.y >> 16);
    }
    float inv = 1.0f / fmaxf((float)(b1 - b0), 1.0f);
    ushort4v o = { f2b(a0 * inv), f2b(a1 * inv), f2b(a2 * inv), f2b(a3 * inv) };
    *reinterpret_cast<ushort4v*>(&bundle[(size_t)n * 256 + 128 + 4 * l]) = o;
}

// ------------- transpose + cast both weights: fp32 [256][C] -> bf16 [C][256] -------------
__global__ void transpose_cast2_kernel(const float* __restrict__ Wf, const float* __restrict__ Wp,
                                       unsigned short* __restrict__ WfT, unsigned short* __restrict__ WpT) {
    __shared__ float tl[32][33];
    int tx = threadIdx.x, ty = threadIdx.y;  // (32, 8)
    int bx = blockIdx.x;
    const float* in; unsigned short* out; int C, cb;
    if (bx < DD / 32) { in = Wf; out = WfT; C = DD; cb = bx; }
    else              { in = Wp; out = WpT; C = AS; cb = bx - DD / 32; }
    int c0 = cb * 32, r0 = blockIdx.y * 32;
    for (int i = 0; i < 4; i++)
        tl[ty + 8 * i][tx] = in[(size_t)(r0 + ty + 8 * i) * C + c0 + tx];
    __syncthreads();
    for (int i = 0; i < 4; i++)
        out[(size_t)(c0 + ty + 8 * i) * 256 + r0 + tx] = f2b(tl[tx][ty + 8 * i]);
}

// ---------------- feat GEMM (m97-style per-iter staging, full-rank swizzle) ----------------
__global__ __launch_bounds__(256) void feat_mfma_kernel(
    const unsigned short* __restrict__ bundle, const unsigned short* __restrict__ WfT,
    const float* __restrict__ bfe, float* __restrict__ feat) {
    __shared__ alignas(16) unsigned short lA[512 * 8];   // 128 rows x 4 units
    __shared__ alignas(16) unsigned short lB[512 * 8];
    __shared__ float red[256];
    int tid = threadIdx.x;
    int r0 = blockIdx.x * 128;
    int wv = tid >> 6, lane = tid & 63;
    int mw = wv >> 1, nw = wv & 1, q = lane >> 4, lm = lane & 15;
    // staging decode: unit u -> row=u>>2, c'=u&3, chunk = c' ^ ((row>>1)&3)
    int rowS0 = tid >> 2,        cS0 = (tid & 3) ^ ((rowS0 >> 1) & 3);
    int rowS1 = (tid + 256) >> 2, cS1 = ((tid + 256) & 3) ^ ((rowS1 >> 1) & 3);
    int swz = q ^ ((lm >> 1) & 3);   // frag-read swizzled chunk

    floatx4 acc[4][4];
#pragma unroll
    for (int mi = 0; mi < 4; mi++)
#pragma unroll
        for (int ni = 0; ni < 4; ni++) acc[mi][ni] = (floatx4)0.f;

    for (int k0 = 0; k0 < 256; k0 += 32) {
        gload16(bundle + (size_t)(r0 + rowS0) * 256 + k0 + 8 * cS0, &lA[tid * 8]);
        gload16(bundle + (size_t)(r0 + rowS1) * 256 + k0 + 8 * cS1, &lA[(tid + 256) * 8]);
        gload16(WfT + (size_t)rowS0 * 256 + k0 + 8 * cS0, &lB[tid * 8]);
        gload16(WfT + (size_t)rowS1 * 256 + k0 + 8 * cS1, &lB[(tid + 256) * 8]);
        __syncthreads();
        short8 aF[4], bF[4];
#pragma unroll
        for (int mi = 0; mi < 4; mi++)
            aF[mi] = *reinterpret_cast<const short8*>(&lA[((64 * mw + 16 * mi + lm) * 4 + swz) * 8]);
#pragma unroll
        for (int ni = 0; ni < 4; ni++)
            bF[ni] = *reinterpret_cast<const short8*>(&lB[((64 * nw + 16 * ni + lm) * 4 + swz) * 8]);
#pragma unroll
        for (int mi = 0; mi < 4; mi++)
#pragma unroll
            for (int ni = 0; ni < 4; ni++)
                acc[mi][ni] = __builtin_amdgcn_mfma_f32_16x16x32_bf16(aF[mi], bF[ni], acc[mi][ni], 0, 0, 0);
        __syncthreads();
    }
    // bias + block-local L2 norm over all 128 cols + relu + store
#pragma unroll
    for (int ni = 0; ni < 4; ni++) {
        float bv = bfe[64 * nw + 16 * ni + lm];
#pragma unroll
        for (int mi = 0; mi < 4; mi++)
#pragma unroll
            for (int r = 0; r < 4; r++) acc[mi][ni][r] += bv;
    }
#pragma unroll
    for (int mi = 0; mi < 4; mi++)
#pragma unroll
        for (int r = 0; r < 4; r++) {
            float p = 0.f;
#pragma unroll
            for (int ni = 0; ni < 4; ni++) p += acc[mi][ni][r] * acc[mi][ni][r];
            p += __shfl_xor(p, 1, 64);
            p += __shfl_xor(p, 2, 64);
            p += __shfl_xor(p, 4, 64);
            p += __shfl_xor(p, 8, 64);
            if (lm == 0) red[nw * 128 + 64 * mw + 16 * mi + 4 * q + r] = p;
        }
    __syncthreads();
#pragma unroll
    for (int mi = 0; mi < 4; mi++)
#pragma unroll
        for (int r = 0; r < 4; r++) {
            int rl = 64 * mw + 16 * mi + 4 * q + r;
            float rn = 1.0f / fmaxf(sqrtf(red[rl] + red[128 + rl]), 1e-12f);
            int row = r0 + rl;
#pragma unroll
            for (int ni = 0; ni < 4; ni++)
                feat[(size_t)row * DD + 64 * nw + 16 * ni + lm] =
                    fmaxf(acc[mi][ni][r] * rn, 0.f);
        }
}

// -------- pool GEMM fused: A-resident (single barrier), B streamed global->VGPR,
// -------- per-row ssq in regs, in-graph strip stash, block-local norm+softmax ----
__global__ __launch_bounds__(256) void pool_fused_kernel(
    const unsigned short* __restrict__ bundle, const unsigned short* __restrict__ WpT,
    const float* __restrict__ bp, float* __restrict__ sArr, unsigned short* __restrict__ sbf) {
    __shared__ alignas(16) unsigned short lA[2048 * 8];  // 64 rows x 256 K, swizzled (32 KB)
    __shared__ float raw[64 * 68];                        // in-graph strip, padded
    __shared__ float ssq_l[4 * 64];
    __shared__ float rn_l[64];
    int tid = threadIdx.x, bx = blockIdx.x;
    int r0 = bx * 64, g = bx >> 3;
    int wv = tid >> 6, lane = tid & 63, q = lane >> 4, lm = lane & 15;

    // stage A once: unit u = row*32 + (chunk ^ (row&7)); dest linear in u
#pragma unroll
    for (int j = 0; j < 8; j++) {
        int u = tid + 256 * j;
        int row = u >> 5;
        int chunk = (u & 31) ^ (row & 7);
        gload16(bundle + (size_t)(r0 + row) * 256 + chunk * 8, &lA[u * 8]);
    }
    float ssqacc[4][4];
#pragma unroll
    for (int mi = 0; mi < 4; mi++)
#pragma unroll
        for (int r = 0; r < 4; r++) ssqacc[mi][r] = 0.f;
    __syncthreads();

    for (int nc8 = 0; nc8 < 8; nc8++) {
        int nc = 4 * nc8 + wv;                      // this wave's 64-col chunk
        const unsigned short* Bb = WpT + ((size_t)(nc * 64 + lm) << 8) + (q << 3);
        short8 bF[2][4];
#pragma unroll
        for (int ni = 0; ni < 4; ni++)
            bF[0][ni] = *reinterpret_cast<const short8*>(Bb + (ni << 12));
        floatx4 acc[4][4];
#pragma unroll
        for (int mi = 0; mi < 4; mi++)
#pragma unroll
            for (int ni = 0; ni < 4; ni++) acc[mi][ni] = (floatx4)0.f;
#pragma unroll
        for (int k = 0; k < 8; k++) {
            if (k < 7) {
#pragma unroll
                for (int ni = 0; ni < 4; ni++)
                    bF[(k + 1) & 1][ni] =
                        *reinterpret_cast<const short8*>(Bb + (ni << 12) + ((k + 1) << 5));
            }
            short8 aF[4];
            int swz = (4 * k + q) ^ (lm & 7);
#pragma unroll
            for (int mi = 0; mi < 4; mi++)
                aF[mi] = *reinterpret_cast<const short8*>(&lA[((16 * mi + lm) * 32 + swz) * 8]);
#pragma unroll
            for (int mi = 0; mi < 4; mi++)
#pragma unroll
                for (int ni = 0; ni < 4; ni++)
                    acc[mi][ni] = __builtin_amdgcn_mfma_f32_16x16x32_bf16(aF[mi], bF[k & 1][ni],
                                                                          acc[mi][ni], 0, 0, 0);
        }
        // bias + lane-local ssq partial (cols ≡ lm mod 16 across this wave's chunks)
        float bv[4];
#pragma unroll
        for (int ni = 0; ni < 4; ni++) bv[ni] = bp[nc * 64 + 16 * ni + lm];
#pragma unroll
        for (int mi = 0; mi < 4; mi++)
#pragma unroll
            for (int r = 0; r < 4; r++) {
                float p = 0.f;
#pragma unroll
                for (int ni = 0; ni < 4; ni++) {
                    acc[mi][ni][r] += bv[ni];
                    p += acc[mi][ni][r] * acc[mi][ni][r];
                }
                ssqacc[mi][r] += p;
            }
        if (nc == g) {   // in-graph strip: stash raw values
#pragma unroll
            for (int mi = 0; mi < 4; mi++)
#pragma unroll
                for (int ni = 0; ni < 4; ni++)
#pragma unroll
                    for (int r = 0; r < 4; r++)
                        raw[(16 * mi + 4 * q + r) * 68 + 16 * ni + lm] = acc[mi][ni][r];
        }
    }
    // finalize ssq: butterfly over lm, publish per wave
#pragma unroll
    for (int mi = 0; mi < 4; mi++)
#pragma unroll
        for (int r = 0; r < 4; r++) {
            float p = ssqacc[mi][r];
            p += __shfl_xor(p, 1, 64);
            p += __shfl_xor(p, 2, 64);
            p += __shfl_xor(p, 4, 64);
            p += __shfl_xor(p, 8, 64);
            if (lm == 0) ssq_l[wv * 64 + 16 * mi + 4 * q + r] = p;
        }
    __syncthreads();
    if (tid < 64)
        rn_l[tid] = 1.0f / fmaxf(sqrtf(ssq_l[tid] + ssq_l[64 + tid] + ssq_l[128 + tid] +
                                       ssq_l[192 + tid]), 1e-12f);
    __syncthreads();
    // softmax over the 64 in-graph cols: 4 threads per row, 16 cols each
    {
        int row = tid >> 2, j = tid & 3;
        float rn = rn_l[row];
        float v[16];
        float mx = -1e30f;
#pragma unroll
        for (int c4 = 0; c4 < 4; c4++) {
            float4 rv = *reinterpret_cast<const float4*>(&raw[row * 68 + 16 * j + 4 * c4]);
            v[4 * c4 + 0] = fmaxf(rv.x * rn, 0.f);
            v[4 * c4 + 1] = fmaxf(rv.y * rn, 0.f);
            v[4 * c4 + 2] = fmaxf(rv.z * rn, 0.f);
            v[4 * c4 + 3] = fmaxf(rv.w * rn, 0.f);
        }
#pragma unroll
        for (int c = 0; c < 16; c++) mx = fmaxf(mx, v[c]);
        mx = fmaxf(mx, __shfl_xor(mx, 1, 64));
        mx = fmaxf(mx, __shfl_xor(mx, 2, 64));
        float z = 0.f;
#pragma unroll
        for (int c = 0; c < 16; c++) { v[c] = __expf(v[c] - mx); z += v[c]; }
        z += __shfl_xor(z, 1, 64);
        z += __shfl_xor(z, 2, 64);
        float iz = 1.0f / z;
        size_t ob = (size_t)(r0 + row) * KC + 16 * j;
#pragma unroll
        for (int c4 = 0; c4 < 4; c4++) {
            float4 o = { v[4 * c4] * iz, v[4 * c4 + 1] * iz, v[4 * c4 + 2] * iz, v[4 * c4 + 3] * iz };
            *reinterpret_cast<float4*>(&sArr[ob + 4 * c4]) = o;
            ushort4v ob16 = { f2b(o.x), f2b(o.y), f2b(o.z), f2b(o.w) };
            *reinterpret_cast<ushort4v*>(&sbf[ob + 4 * c4]) = ob16;
        }
    }
}

// ------- a_s = segment_sum(s[src], dst): gather bf16 s, fp32 accumulate -------
__global__ void agg_s_kernel(const unsigned short* __restrict__ sbf, const int* __restrict__ off,
                             const int* __restrict__ csr, float* __restrict__ as_) {
    int t = threadIdx.x;                 // 256 = 16 nodes x 16 lanes
    int n = blockIdx.x * 16 + (t >> 4);
    int l = t & 15;
    const uint2* s2 = reinterpret_cast<const uint2*>(sbf);   // row = 16 uint2
    int b0 = off[n], b1 = off[n + 1];
    float a0 = 0.f, a1 = 0.f, a2 = 0.f, a3 = 0.f;
    for (int i = b0; i < b1; i++) {
        uint2 v = s2[(size_t)csr[i] * 16 + l];
        a0 += bits2f(v.x & 0xffffu); a1 += bits2f(v.x >> 16);
        a2 += bits2f(v.y & 0xffffu); a3 += bits2f(v.y >> 16);
    }
    float4 o = { a0, a1, a2, a3 };
    reinterpret_cast<float4*>(as_)[(size_t)n * 16 + l] = o;
}

// ---------------- h_new = s^T feat, per-graph [64x128] ----------------
__global__ void hnew_kernel(const float* __restrict__ s, const float* __restrict__ feat,
                            float* __restrict__ hnewf) {
    int g = blockIdx.y, ch = blockIdx.x;  // 4 chunks of 128 nodes
    int t = threadIdx.x;                  // 256
    __shared__ float s_sub[32][64];
    __shared__ float f_sub[32][128];
    int col = t & 127, half = t >> 7;
    float acc[32];
#pragma unroll
    for (int i = 0; i < 32; i++) acc[i] = 0.f;
    int nbase0 = g * NPER + ch * 128;
    for (int sub = 0; sub < 4; sub++) {
        int nbase = nbase0 + sub * 32;
        for (int q = 0; q < 8; q++) {
            int idx = t + 256 * q;
            ((float*)s_sub)[idx] = s[(size_t)nbase * KC + idx];
        }
        for (int q = 0; q < 16; q++) {
            int idx = t + 256 * q;
            ((float*)f_sub)[idx] = feat[(size_t)nbase * DD + idx];
        }
        __syncthreads();
        for (int nd = 0; nd < 32; nd++) {
            float f = f_sub[nd][col];
#pragma unroll
            for (int i = 0; i < 32; i++) acc[i] += s_sub[nd][half + 2 * i] * f;
        }
        __syncthreads();
    }
    for (int i = 0; i < 32; i++) {
        int c = half + 2 * i;
        atomicAdd(&hnewf[(size_t)(g * KC + c) * DD + col], acc[i]);
    }
}

// ---------------- adj diag blocks: s^T a_s, per-graph [64x64] ----------------
__global__ void adj_kernel(const float* __restrict__ s, const float* __restrict__ as_,
                           float* __restrict__ adjf) {
    int g = blockIdx.y, ch = blockIdx.x;  // 4 chunks of 128 nodes
    int t = threadIdx.x;                  // 256
    __shared__ float s1[64][64];
    __shared__ float a2[64][64];
    int c2 = t & 63, q = t >> 6;
    float acc[16];
#pragma unroll
    for (int i = 0; i < 16; i++) acc[i] = 0.f;
    int nbase0 = g * NPER + ch * 128;
    for (int sub = 0; sub < 2; sub++) {
        int nbase = nbase0 + sub * 64;
        for (int qq = 0; qq < 16; qq++) {
            int idx = t + 256 * qq;
            ((float*)s1)[idx] = s[(size_t)nbase * KC + idx];
            ((float*)a2)[idx] = as_[(size_t)nbase * KC + idx];
        }
        __syncthreads();
        for (int nd = 0; nd < 64; nd++) {
            float av = a2[nd][c2];
#pragma unroll
            for (int i = 0; i < 16; i++) acc[i] += s1[nd][q + 4 * i] * av;
        }
        __syncthreads();
    }
    for (int i = 0; i < 16; i++) {
        int c1 = q + 4 * i;
        atomicAdd(&adjf[(size_t)(g * KC + c1) * AS + g * KC + c2], acc[i]);
    }
}

extern "C" void kernel_launch(void* const* d_in, const int* in_sizes, int n_in,
                              void* d_out, int out_size, void* d_ws, size_t ws_size,
                              hipStream_t stream) {
    const float* h   = (const float*)d_in[0];
    const float* Wf  = (const float*)d_in[1];
    const float* bfe = (const float*)d_in[2];
    const float* Wp  = (const float*)d_in[3];
    const float* bp  = (const float*)d_in[4];
    const int* esrc  = (const int*)d_in[5];
    const int* edst  = (const int*)d_in[6];

    // outputs accumulate directly into d_out (fp32): [adj 2048x2048][h_new 2048x128]
    float* adjf  = (float*)d_out;
    float* hnewf = adjf + (size_t)AS * AS;

    float* wsf = (float*)d_ws;
    float* sArr  = wsf;                               // NN*KC fp32
    float* asArr = sArr + (size_t)NN * KC;            // NN*KC fp32
    float* feat  = asArr + (size_t)NN * KC;           // NN*DD fp32
    unsigned short* bundle = (unsigned short*)(feat + (size_t)NN * DD);  // NN*256 bf16
    unsigned short* WfT = bundle + (size_t)NN * 256;  // 128*256 bf16
    unsigned short* WpT = WfT + 128 * 256;            // 2048*256 bf16
    unsigned short* sbf = WpT + (size_t)AS * 256;     // NN*KC bf16
    int* cnt    = (int*)(sbf + (size_t)NN * KC);
    int* off    = cnt + NN;
    int* cursor = off + NN + 1;
    int* csr    = cursor + NN;

    hipMemsetAsync(cnt, 0, NN * sizeof(int), stream);
    hipMemsetAsync(d_out, 0, ((size_t)AS * AS + (size_t)AS * DD) * sizeof(float), stream);

    count_kernel<<<EE / 256, 256, 0, stream>>>(edst, cnt);
    scan_kernel<<<1, 256, 0, stream>>>(cnt, off, cursor);
    scatter_kernel<<<EE / 256, 256, 0, stream>>>(esrc, edst, cursor, csr);

    cast_h_kernel<<<NN * DD / 4 / 256, 256, 0, stream>>>(h, bundle);
    agg_h_kernel<<<NN / 8, 256, 0, stream>>>(bundle, off, csr);

    transpose_cast2_kernel<<<dim3(DD / 32 + AS / 32, 256 / 32), dim3(32, 8), 0, stream>>>(
        Wf, Wp, WfT, WpT);

    feat_mfma_kernel<<<NN / 128, 256, 0, stream>>>(bundle, WfT, bfe, feat);
    pool_fused_kernel<<<NN / 64, 256, 0, stream>>>(bundle, WpT, bp, sArr, sbf);

    agg_s_kernel<<<NN / 16, 256, 0, stream>>>(sbf, off, csr, asArr);
    hnew_kernel<<<dim3(4, NB), 256, 0, stream>>>(sArr, feat, hnewf);
    adj_kernel<<<dim3(4, NB), 256, 0, stream>>>(sArr, asArr, adjf);
}

// Round 6
// 205.272 us; speedup vs baseline: 2.1447x; 1.1239x over previous
//
#include <hip/hip_runtime.h>

#define NB   32      // graphs
#define NPER 512     // nodes per graph
#define NN   16384   // total nodes
#define EE   262144  // edges
#define DD   128     // D_IN == D_OUT
#define AS   2048    // total clusters
#define KC   64      // clusters per graph

using short8   = __attribute__((ext_vector_type(8))) short;   // 8 bf16 (4 VGPRs)
using floatx4  = __attribute__((ext_vector_type(4))) float;   // MFMA acc
using ushort4v = __attribute__((ext_vector_type(4))) unsigned short;

typedef __attribute__((address_space(3))) unsigned int lds_u32;
typedef const __attribute__((address_space(1))) unsigned int gbl_u32;

// async 16B global -> LDS (wave-uniform base + lane*16; keep dest linear in tid)
static __device__ __forceinline__ void gload16(const unsigned short* g, unsigned short* l) {
    __builtin_amdgcn_global_load_lds((gbl_u32*)g, (lds_u32*)l, 16, 0, 0);
}

static __device__ __forceinline__ float bits2f(unsigned int u) {
    union { unsigned int i; float f; } z; z.i = u << 16; return z.f;
}
// float -> bf16 bits, round-to-nearest-even
static __device__ __forceinline__ unsigned short f2b(float x) {
    union { float f; unsigned int u; } v; v.f = x;
    unsigned int r = v.u + 0x7fffu + ((v.u >> 16) & 1u);
    return (unsigned short)(r >> 16);
}

// ---------------- fused: cast h -> bundle (blocks 0..2047) + degree count (2048..3071) ----
__global__ void prep_kernel(const float* __restrict__ h, unsigned short* __restrict__ bundle,
                            const int* __restrict__ edst, int* __restrict__ cnt) {
    int b = blockIdx.x;
    if (b < 2048) {
        int gid = b * 256 + threadIdx.x;        // one float4 each, NN*DD/4 total
        float4 v = reinterpret_cast<const float4*>(h)[gid];
        int f = gid << 2;
        int n = f >> 7, c = f & 127;
        ushort4v o = { f2b(v.x), f2b(v.y), f2b(v.z), f2b(v.w) };
        *reinterpret_cast<ushort4v*>(&bundle[(size_t)n * 256 + c]) = o;
    } else {
        int e = (b - 2048) * 256 + threadIdx.x; // EE/256 = 1024 blocks
        atomicAdd(&cnt[edst[e]], 1);
    }
}

__global__ void scan_kernel(const int* __restrict__ cnt, int* __restrict__ off,
                            int* __restrict__ cursor) {
    __shared__ int sums[256];
    int t = threadIdx.x;
    int base = t * 64;
    int sum = 0;
    for (int i = 0; i < 64; i++) sum += cnt[base + i];
    sums[t] = sum;
    __syncthreads();
    for (int d = 1; d < 256; d <<= 1) {
        int add = (t >= d) ? sums[t - d] : 0;
        __syncthreads();
        sums[t] += add;
        __syncthreads();
    }
    int run = (t == 0) ? 0 : sums[t - 1];
    for (int i = 0; i < 64; i++) {
        off[base + i] = run;
        cursor[base + i] = run;
        run += cnt[base + i];
    }
    if (t == 255) off[NN] = run;
}

__global__ void scatter_kernel(const int* __restrict__ esrc, const int* __restrict__ edst,
                               int* __restrict__ cursor, int* __restrict__ csr) {
    int e = blockIdx.x * 256 + threadIdx.x;
    int p = atomicAdd(&cursor[edst[e]], 1);
    csr[p] = esrc[e];
}

// ------- neighbor mean: gather bf16 lower half -> write upper half (bf16) -------
__global__ void agg_h_kernel(unsigned short* __restrict__ bundle, const int* __restrict__ off,
                             const int* __restrict__ csr) {
    int t = threadIdx.x;                 // 256 = 8 nodes x 32 lanes
    int n = blockIdx.x * 8 + (t >> 5);
    int l = t & 31;
    const uint2* b2 = reinterpret_cast<const uint2*>(bundle);  // row = 64 uint2
    int b0 = off[n], b1 = off[n + 1];
    float a0 = 0.f, a1 = 0.f, a2 = 0.f, a3 = 0.f;
    for (int i = b0; i < b1; i++) {
        int s = csr[i];
        uint2 v = b2[(size_t)s * 64 + l];
        a0 += bits2f(v.x & 0xffffu); a1 += bits2f(v.x >> 16);
        a2 += bits2f(v.y & 0xffffu); a3 += bits2f(v.y >> 16);
    }
    float inv = 1.0f / fmaxf((float)(b1 - b0), 1.0f);
    ushort4v o = { f2b(a0 * inv), f2b(a1 * inv), f2b(a2 * inv), f2b(a3 * inv) };
    *reinterpret_cast<ushort4v*>(&bundle[(size_t)n * 256 + 128 + 4 * l]) = o;
}

// ------------- transpose + cast both weights: fp32 [256][C] -> bf16 [C][256] -------------
__global__ void transpose_cast2_kernel(const float* __restrict__ Wf, const float* __restrict__ Wp,
                                       unsigned short* __restrict__ WfT, unsigned short* __restrict__ WpT) {
    __shared__ float tl[32][33];
    int tx = threadIdx.x, ty = threadIdx.y;  // (32, 8)
    int bx = blockIdx.x;
    const float* in; unsigned short* out; int C, cb;
    if (bx < DD / 32) { in = Wf; out = WfT; C = DD; cb = bx; }
    else              { in = Wp; out = WpT; C = AS; cb = bx - DD / 32; }
    int c0 = cb * 32, r0 = blockIdx.y * 32;
    for (int i = 0; i < 4; i++)
        tl[ty + 8 * i][tx] = in[(size_t)(r0 + ty + 8 * i) * C + c0 + tx];
    __syncthreads();
    for (int i = 0; i < 4; i++)
        out[(size_t)(c0 + ty + 8 * i) * 256 + r0 + tx] = f2b(tl[tx][ty + 8 * i]);
}

// ------- feat GEMM (MFMA) + bias + L2norm + relu -> featT bf16 [col][node] -------
__global__ __launch_bounds__(256) void feat_mfma_kernel(
    const unsigned short* __restrict__ bundle, const unsigned short* __restrict__ WfT,
    const float* __restrict__ bfe, unsigned short* __restrict__ featT) {
    __shared__ alignas(16) unsigned short lA[512 * 8];   // 128 rows x 4 units
    __shared__ alignas(16) unsigned short lB[512 * 8];
    __shared__ float red[256];
    __shared__ alignas(16) unsigned short fT[128 * 136]; // transpose buffer [col][rowInBlk]
    int tid = threadIdx.x;
    int r0 = blockIdx.x * 128;
    int wv = tid >> 6, lane = tid & 63;
    int mw = wv >> 1, nw = wv & 1, q = lane >> 4, lm = lane & 15;
    int rowS0 = tid >> 2,         cS0 = (tid & 3) ^ ((rowS0 >> 1) & 3);
    int rowS1 = (tid + 256) >> 2, cS1 = ((tid + 256) & 3) ^ ((rowS1 >> 1) & 3);
    int swz = q ^ ((lm >> 1) & 3);

    floatx4 acc[4][4];
#pragma unroll
    for (int mi = 0; mi < 4; mi++)
#pragma unroll
        for (int ni = 0; ni < 4; ni++) acc[mi][ni] = (floatx4)0.f;

    for (int k0 = 0; k0 < 256; k0 += 32) {
        gload16(bundle + (size_t)(r0 + rowS0) * 256 + k0 + 8 * cS0, &lA[tid * 8]);
        gload16(bundle + (size_t)(r0 + rowS1) * 256 + k0 + 8 * cS1, &lA[(tid + 256) * 8]);
        gload16(WfT + (size_t)rowS0 * 256 + k0 + 8 * cS0, &lB[tid * 8]);
        gload16(WfT + (size_t)rowS1 * 256 + k0 + 8 * cS1, &lB[(tid + 256) * 8]);
        __syncthreads();
        short8 aF[4], bF[4];
#pragma unroll
        for (int mi = 0; mi < 4; mi++)
            aF[mi] = *reinterpret_cast<const short8*>(&lA[((64 * mw + 16 * mi + lm) * 4 + swz) * 8]);
#pragma unroll
        for (int ni = 0; ni < 4; ni++)
            bF[ni] = *reinterpret_cast<const short8*>(&lB[((64 * nw + 16 * ni + lm) * 4 + swz) * 8]);
#pragma unroll
        for (int mi = 0; mi < 4; mi++)
#pragma unroll
            for (int ni = 0; ni < 4; ni++)
                acc[mi][ni] = __builtin_amdgcn_mfma_f32_16x16x32_bf16(aF[mi], bF[ni], acc[mi][ni], 0, 0, 0);
        __syncthreads();
    }
#pragma unroll
    for (int ni = 0; ni < 4; ni++) {
        float bv = bfe[64 * nw + 16 * ni + lm];
#pragma unroll
        for (int mi = 0; mi < 4; mi++)
#pragma unroll
            for (int r = 0; r < 4; r++) acc[mi][ni][r] += bv;
    }
#pragma unroll
    for (int mi = 0; mi < 4; mi++)
#pragma unroll
        for (int r = 0; r < 4; r++) {
            float p = 0.f;
#pragma unroll
            for (int ni = 0; ni < 4; ni++) p += acc[mi][ni][r] * acc[mi][ni][r];
            p += __shfl_xor(p, 1, 64);
            p += __shfl_xor(p, 2, 64);
            p += __shfl_xor(p, 4, 64);
            p += __shfl_xor(p, 8, 64);
            if (lm == 0) red[nw * 128 + 64 * mw + 16 * mi + 4 * q + r] = p;
        }
    __syncthreads();
#pragma unroll
    for (int mi = 0; mi < 4; mi++) {
        float rrn[4];
#pragma unroll
        for (int r = 0; r < 4; r++) {
            int rl = 64 * mw + 16 * mi + 4 * q + r;
            rrn[r] = 1.0f / fmaxf(sqrtf(red[rl] + red[128 + rl]), 1e-12f);
        }
#pragma unroll
        for (int ni = 0; ni < 4; ni++) {
            int col = 64 * nw + 16 * ni + lm;
            ushort4v pk = { f2b(fmaxf(acc[mi][ni][0] * rrn[0], 0.f)),
                            f2b(fmaxf(acc[mi][ni][1] * rrn[1], 0.f)),
                            f2b(fmaxf(acc[mi][ni][2] * rrn[2], 0.f)),
                            f2b(fmaxf(acc[mi][ni][3] * rrn[3], 0.f)) };
            *reinterpret_cast<ushort4v*>(&fT[col * 136 + 64 * mw + 16 * mi + 4 * q]) = pk;
        }
    }
    __syncthreads();
    {   // store featT: thread -> (col, half), 64 shorts = 8 x uint4
        int col = tid >> 1, half = tid & 1;
        const uint4* src = reinterpret_cast<const uint4*>(&fT[col * 136 + half * 64]);
        uint4* dst = reinterpret_cast<uint4*>(featT + (size_t)col * NN + r0 + half * 64);
#pragma unroll
        for (int i = 0; i < 8; i++) dst[i] = src[i];
    }
}

// -------- pool GEMM fused: A-resident, B streamed global->VGPR, ssq in regs,
// -------- block-local norm+relu+softmax; outputs sbf [node][cl] + sT [cl][node] ----
__global__ __launch_bounds__(256) void pool_fused_kernel(
    const unsigned short* __restrict__ bundle, const unsigned short* __restrict__ WpT,
    const float* __restrict__ bp, unsigned short* __restrict__ sbf,
    unsigned short* __restrict__ sT) {
    __shared__ alignas(16) unsigned short lA[2048 * 8];  // 64 rows x 256 K, swizzled (32 KB)
    __shared__ float raw[64 * 68];                        // in-graph strip, padded
    __shared__ float ssq_l[4 * 64];
    __shared__ float rn_l[64];
    int tid = threadIdx.x, bx = blockIdx.x;
    int r0 = bx * 64, g = bx >> 3;
    int wv = tid >> 6, lane = tid & 63, q = lane >> 4, lm = lane & 15;

#pragma unroll
    for (int j = 0; j < 8; j++) {
        int u = tid + 256 * j;
        int row = u >> 5;
        int chunk = (u & 31) ^ (row & 7);
        gload16(bundle + (size_t)(r0 + row) * 256 + chunk * 8, &lA[u * 8]);
    }
    float ssqacc[4][4];
#pragma unroll
    for (int mi = 0; mi < 4; mi++)
#pragma unroll
        for (int r = 0; r < 4; r++) ssqacc[mi][r] = 0.f;
    __syncthreads();

    for (int nc8 = 0; nc8 < 8; nc8++) {
        int nc = 4 * nc8 + wv;
        const unsigned short* Bb = WpT + ((size_t)(nc * 64 + lm) << 8) + (q << 3);
        short8 bF[2][4];
#pragma unroll
        for (int ni = 0; ni < 4; ni++)
            bF[0][ni] = *reinterpret_cast<const short8*>(Bb + (ni << 12));
        floatx4 acc[4][4];
#pragma unroll
        for (int mi = 0; mi < 4; mi++)
#pragma unroll
            for (int ni = 0; ni < 4; ni++) acc[mi][ni] = (floatx4)0.f;
#pragma unroll
        for (int k = 0; k < 8; k++) {
            if (k < 7) {
#pragma unroll
                for (int ni = 0; ni < 4; ni++)
                    bF[(k + 1) & 1][ni] =
                        *reinterpret_cast<const short8*>(Bb + (ni << 12) + ((k + 1) << 5));
            }
            short8 aF[4];
            int swz = (4 * k + q) ^ (lm & 7);
#pragma unroll
            for (int mi = 0; mi < 4; mi++)
                aF[mi] = *reinterpret_cast<const short8*>(&lA[((16 * mi + lm) * 32 + swz) * 8]);
#pragma unroll
            for (int mi = 0; mi < 4; mi++)
#pragma unroll
                for (int ni = 0; ni < 4; ni++)
                    acc[mi][ni] = __builtin_amdgcn_mfma_f32_16x16x32_bf16(aF[mi], bF[k & 1][ni],
                                                                          acc[mi][ni], 0, 0, 0);
        }
        float bv[4];
#pragma unroll
        for (int ni = 0; ni < 4; ni++) bv[ni] = bp[nc * 64 + 16 * ni + lm];
#pragma unroll
        for (int mi = 0; mi < 4; mi++)
#pragma unroll
            for (int r = 0; r < 4; r++) {
                float p = 0.f;
#pragma unroll
                for (int ni = 0; ni < 4; ni++) {
                    acc[mi][ni][r] += bv[ni];
                    p += acc[mi][ni][r] * acc[mi][ni][r];
                }
                ssqacc[mi][r] += p;
            }
        if (nc == g) {
#pragma unroll
            for (int mi = 0; mi < 4; mi++)
#pragma unroll
                for (int ni = 0; ni < 4; ni++)
#pragma unroll
                    for (int r = 0; r < 4; r++)
                        raw[(16 * mi + 4 * q + r) * 68 + 16 * ni + lm] = acc[mi][ni][r];
        }
    }
#pragma unroll
    for (int mi = 0; mi < 4; mi++)
#pragma unroll
        for (int r = 0; r < 4; r++) {
            float p = ssqacc[mi][r];
            p += __shfl_xor(p, 1, 64);
            p += __shfl_xor(p, 2, 64);
            p += __shfl_xor(p, 4, 64);
            p += __shfl_xor(p, 8, 64);
            if (lm == 0) ssq_l[wv * 64 + 16 * mi + 4 * q + r] = p;
        }
    __syncthreads();
    if (tid < 64)
        rn_l[tid] = 1.0f / fmaxf(sqrtf(ssq_l[tid] + ssq_l[64 + tid] + ssq_l[128 + tid] +
                                       ssq_l[192 + tid]), 1e-12f);
    __syncthreads();
    {   // softmax over the 64 in-graph cols: 4 threads per row, 16 cols each
        int row = tid >> 2, j = tid & 3;
        int nloc = ((bx & 7) << 6) + row;     // node index within graph
        float rn = rn_l[row];
        float v[16];
        float mx = -1e30f;
#pragma unroll
        for (int c4 = 0; c4 < 4; c4++) {
            float4 rv = *reinterpret_cast<const float4*>(&raw[row * 68 + 16 * j + 4 * c4]);
            v[4 * c4 + 0] = fmaxf(rv.x * rn, 0.f);
            v[4 * c4 + 1] = fmaxf(rv.y * rn, 0.f);
            v[4 * c4 + 2] = fmaxf(rv.z * rn, 0.f);
            v[4 * c4 + 3] = fmaxf(rv.w * rn, 0.f);
        }
#pragma unroll
        for (int c = 0; c < 16; c++) mx = fmaxf(mx, v[c]);
        mx = fmaxf(mx, __shfl_xor(mx, 1, 64));
        mx = fmaxf(mx, __shfl_xor(mx, 2, 64));
        float z = 0.f;
#pragma unroll
        for (int c = 0; c < 16; c++) { v[c] = __expf(v[c] - mx); z += v[c]; }
        z += __shfl_xor(z, 1, 64);
        z += __shfl_xor(z, 2, 64);
        float iz = 1.0f / z;
        size_t ob = (size_t)(r0 + row) * KC + 16 * j;
#pragma unroll
        for (int c4 = 0; c4 < 4; c4++) {
            unsigned short b0 = f2b(v[4 * c4 + 0] * iz), b1 = f2b(v[4 * c4 + 1] * iz);
            unsigned short b2 = f2b(v[4 * c4 + 2] * iz), b3 = f2b(v[4 * c4 + 3] * iz);
            ushort4v pk = { b0, b1, b2, b3 };
            *reinterpret_cast<ushort4v*>(&sbf[ob + 4 * c4]) = pk;
            // transposed copy sT[(g*64+c)*512 + nloc]
            size_t tb = (size_t)(g * KC + 16 * j + 4 * c4) * NPER + nloc;
            sT[tb] = b0; sT[tb + NPER] = b1; sT[tb + 2 * NPER] = b2; sT[tb + 3 * NPER] = b3;
        }
    }
}

// ------- a_s = segment_sum(s[src], dst): gather bf16 s -> asT bf16 [cl][node] -------
__global__ void agg_s_kernel(const unsigned short* __restrict__ sbf, const int* __restrict__ off,
                             const int* __restrict__ csr, unsigned short* __restrict__ asT) {
    int t = threadIdx.x;                 // 256 = 16 nodes x 16 lanes
    int n = blockIdx.x * 16 + (t >> 4);
    int l = t & 15;
    int g = n >> 9, nloc = n & 511;
    const uint2* s2 = reinterpret_cast<const uint2*>(sbf);   // row = 16 uint2
    int b0 = off[n], b1 = off[n + 1];
    float a0 = 0.f, a1 = 0.f, a2 = 0.f, a3 = 0.f;
    for (int i = b0; i < b1; i++) {
        uint2 v = s2[(size_t)csr[i] * 16 + l];
        a0 += bits2f(v.x & 0xffffu); a1 += bits2f(v.x >> 16);
        a2 += bits2f(v.y & 0xffffu); a3 += bits2f(v.y >> 16);
    }
    size_t tb = (size_t)(g * KC + 4 * l) * NPER + nloc;
    asT[tb] = f2b(a0); asT[tb + NPER] = f2b(a1);
    asT[tb + 2 * NPER] = f2b(a2); asT[tb + 3 * NPER] = f2b(a3);
}

// ------- fused h_new + adj via MFMA: per (graph, 128-node chunk) block ---------
// waves 0,1: hnew cols 0-63 / 64-127 (K=128); waves 2,3: adj cols, K split 64/64.
__global__ __launch_bounds__(256) void hnew_adj_kernel(
    const unsigned short* __restrict__ sT, const unsigned short* __restrict__ featT,
    const unsigned short* __restrict__ asT, float* __restrict__ adjf,
    float* __restrict__ hnewf) {
    __shared__ alignas(16) unsigned short lS[1024 * 8];   // 64 x 128 (16 KB)
    __shared__ alignas(16) unsigned short lF[2048 * 8];   // 128 x 128 (32 KB)
    __shared__ alignas(16) unsigned short lAS[1024 * 8];  // 64 x 128 (16 KB)
    int tid = threadIdx.x;
    int ch = blockIdx.x, g = blockIdx.y;
    int k0 = g * NPER + ch * 128;         // global node base for featT
    int wv = tid >> 6, lane = tid & 63, q = lane >> 4, lm = lane & 15;

#pragma unroll
    for (int j = 0; j < 4; j++) {         // sT tile
        int u = tid + 256 * j;
        int row = u >> 4, cu = (u & 15) ^ (row & 15);
        gload16(sT + (size_t)(g * KC + row) * NPER + ch * 128 + cu * 8, &lS[u * 8]);
    }
#pragma unroll
    for (int j = 0; j < 8; j++) {         // featT tile
        int u = tid + 256 * j;
        int row = u >> 4, cu = (u & 15) ^ (row & 15);
        gload16(featT + (size_t)row * NN + k0 + cu * 8, &lF[u * 8]);
    }
#pragma unroll
    for (int j = 0; j < 4; j++) {         // asT tile
        int u = tid + 256 * j;
        int row = u >> 4, cu = (u & 15) ^ (row & 15);
        gload16(asT + (size_t)(g * KC + row) * NPER + ch * 128 + cu * 8, &lAS[u * 8]);
    }
    floatx4 acc[4][4];
#pragma unroll
    for (int mi = 0; mi < 4; mi++)
#pragma unroll
        for (int ni = 0; ni < 4; ni++) acc[mi][ni] = (floatx4)0.f;
    __syncthreads();

    bool isH = (wv < 2);
    for (int ks = 0; ks < 4; ks++) {
        if (!isH && (ks >> 1) != (wv & 1)) continue;   // waves 2/3 split K
        short8 aF[4], bF[4];
#pragma unroll
        for (int mi = 0; mi < 4; mi++)
            aF[mi] = *reinterpret_cast<const short8*>(
                &lS[((16 * mi + lm) * 16 + ((4 * ks + q) ^ lm)) * 8]);
        if (isH) {
#pragma unroll
            for (int ni = 0; ni < 4; ni++)
                bF[ni] = *reinterpret_cast<const short8*>(
                    &lF[((64 * wv + 16 * ni + lm) * 16 + ((4 * ks + q) ^ lm)) * 8]);
        } else {
#pragma unroll
            for (int ni = 0; ni < 4; ni++)
                bF[ni] = *reinterpret_cast<const short8*>(
                    &lAS[((16 * ni + lm) * 16 + ((4 * ks + q) ^ lm)) * 8]);
        }
#pragma unroll
        for (int mi = 0; mi < 4; mi++)
#pragma unroll
            for (int ni = 0; ni < 4; ni++)
                acc[mi][ni] = __builtin_amdgcn_mfma_f32_16x16x32_bf16(aF[mi], bF[ni], acc[mi][ni], 0, 0, 0);
    }
    if (isH) {
#pragma unroll
        for (int mi = 0; mi < 4; mi++)
#pragma unroll
            for (int ni = 0; ni < 4; ni++)
#pragma unroll
                for (int r = 0; r < 4; r++)
                    atomicAdd(&hnewf[(size_t)(g * KC + 16 * mi + 4 * q + r) * DD +
                                     64 * wv + 16 * ni + lm], acc[mi][ni][r]);
    } else {
#pragma unroll
        for (int mi = 0; mi < 4; mi++)
#pragma unroll
            for (int ni = 0; ni < 4; ni++)
#pragma unroll
                for (int r = 0; r < 4; r++)
                    atomicAdd(&adjf[(size_t)(g * KC + 16 * mi + 4 * q + r) * AS +
                                    g * KC + 16 * ni + lm], acc[mi][ni][r]);
    }
}

extern "C" void kernel_launch(void* const* d_in, const int* in_sizes, int n_in,
                              void* d_out, int out_size, void* d_ws, size_t ws_size,
                              hipStream_t stream) {
    const float* h   = (const float*)d_in[0];
    const float* Wf  = (const float*)d_in[1];
    const float* bfe = (const float*)d_in[2];
    const float* Wp  = (const float*)d_in[3];
    const float* bp  = (const float*)d_in[4];
    const int* esrc  = (const int*)d_in[5];
    const int* edst  = (const int*)d_in[6];

    // outputs accumulate directly into d_out (fp32): [adj 2048x2048][h_new 2048x128]
    float* adjf  = (float*)d_out;
    float* hnewf = adjf + (size_t)AS * AS;

    unsigned short* bundle = (unsigned short*)d_ws;        // NN*256 bf16
    unsigned short* WfT   = bundle + (size_t)NN * 256;     // 128*256
    unsigned short* WpT   = WfT + 128 * 256;               // 2048*256
    unsigned short* sbf   = WpT + (size_t)AS * 256;        // NN*KC   [node][cl]
    unsigned short* sT    = sbf + (size_t)NN * KC;         // NN*KC   [g*64+cl][node]
    unsigned short* asT   = sT + (size_t)NN * KC;          // NN*KC   [g*64+cl][node]
    unsigned short* featT = asT + (size_t)NN * KC;         // DD*NN   [col][node]
    int* cnt    = (int*)(featT + (size_t)DD * NN);
    int* off    = cnt + NN;
    int* cursor = off + NN + 1;
    int* csr    = cursor + NN;

    hipMemsetAsync(cnt, 0, NN * sizeof(int), stream);
    hipMemsetAsync(d_out, 0, ((size_t)AS * AS + (size_t)AS * DD) * sizeof(float), stream);

    prep_kernel<<<2048 + EE / 256, 256, 0, stream>>>(h, bundle, edst, cnt);
    scan_kernel<<<1, 256, 0, stream>>>(cnt, off, cursor);
    scatter_kernel<<<EE / 256, 256, 0, stream>>>(esrc, edst, cursor, csr);
    agg_h_kernel<<<NN / 8, 256, 0, stream>>>(bundle, off, csr);

    transpose_cast2_kernel<<<dim3(DD / 32 + AS / 32, 256 / 32), dim3(32, 8), 0, stream>>>(
        Wf, Wp, WfT, WpT);

    feat_mfma_kernel<<<NN / 128, 256, 0, stream>>>(bundle, WfT, bfe, featT);
    pool_fused_kernel<<<NN / 64, 256, 0, stream>>>(bundle, WpT, bp, sbf, sT);

    agg_s_kernel<<<NN / 16, 256, 0, stream>>>(sbf, off, csr, asT);
    hnew_adj_kernel<<<dim3(4, NB), 256, 0, stream>>>(sT, featT, asT, adjf, hnewf);
}

// Round 7
// 185.720 us; speedup vs baseline: 2.3705x; 1.1053x over previous
//
#include <hip/hip_runtime.h>

#define NB   32      // graphs
#define NPER 512     // nodes per graph
#define NN   16384   // total nodes
#define EE   262144  // edges
#define DD   128     // D_IN == D_OUT
#define AS   2048    // total clusters
#define KC   64      // clusters per graph

using short8   = __attribute__((ext_vector_type(8))) short;   // 8 bf16 (4 VGPRs)
using floatx4  = __attribute__((ext_vector_type(4))) float;   // MFMA acc
using ushort4v = __attribute__((ext_vector_type(4))) unsigned short;

typedef __attribute__((address_space(3))) unsigned int lds_u32;
typedef const __attribute__((address_space(1))) unsigned int gbl_u32;

// async 16B global -> LDS (wave-uniform base + lane*16; keep dest linear in tid)
static __device__ __forceinline__ void gload16(const unsigned short* g, unsigned short* l) {
    __builtin_amdgcn_global_load_lds((gbl_u32*)g, (lds_u32*)l, 16, 0, 0);
}

static __device__ __forceinline__ float bits2f(unsigned int u) {
    union { unsigned int i; float f; } z; z.i = u << 16; return z.f;
}
// float -> bf16 bits, round-to-nearest-even
static __device__ __forceinline__ unsigned short f2b(float x) {
    union { float f; unsigned int u; } v; v.f = x;
    unsigned int r = v.u + 0x7fffu + ((v.u >> 16) & 1u);
    return (unsigned short)(r >> 16);
}

// ---- prep: blocks 0-127 cast h -> bundle lower + hT transpose; 128.. count dense A ----
__global__ void prep_kernel(const float* __restrict__ h, unsigned short* __restrict__ bundle,
                            unsigned short* __restrict__ hT, const int* __restrict__ esrc,
                            const int* __restrict__ edst, unsigned int* __restrict__ Acnt) {
    __shared__ unsigned short fT[128 * 136];   // [col][row], row-dim padded (272 B, 16B-aligned)
    int b = blockIdx.x, t = threadIdx.x;
    if (b < 128) {
        int node0 = b * 128;
        int r = t >> 1, hf = t & 1;
        const float4* h4 = reinterpret_cast<const float4*>(h + (size_t)(node0 + r) * 128 + hf * 64);
        unsigned short* bo = bundle + (size_t)(node0 + r) * 256 + hf * 64;
#pragma unroll
        for (int i = 0; i < 16; i++) {
            float4 v = h4[i];
            ushort4v o = { f2b(v.x), f2b(v.y), f2b(v.z), f2b(v.w) };
            *reinterpret_cast<ushort4v*>(bo + 4 * i) = o;
            int c = hf * 64 + 4 * i;
            fT[(c + 0) * 136 + r] = o.x;
            fT[(c + 1) * 136 + r] = o.y;
            fT[(c + 2) * 136 + r] = o.z;
            fT[(c + 3) * 136 + r] = o.w;
        }
        __syncthreads();
        int c = t >> 1, nh = t & 1;
        const uint4* src = reinterpret_cast<const uint4*>(&fT[c * 136 + nh * 64]);
        uint4* dst = reinterpret_cast<uint4*>(hT + (size_t)c * NN + node0 + nh * 64);
#pragma unroll
        for (int i = 0; i < 8; i++) dst[i] = src[i];
    } else {
        int e = (b - 128) * 256 + t;           // EE/256 = 1024 blocks
        int d = edst[e], sl = esrc[e] & 511;
        int idx = d * 512 + sl;                // byte index into dense A counts
        atomicAdd(&Acnt[idx >> 2], 1u << (8 * (idx & 3)));
    }
}

// ---- conv: uint8 counts -> A_adj bf16 [dst][512 src] + invdeg (rowsum, exact) ----
__global__ void conv_kernel(const unsigned int* __restrict__ Acnt,
                            unsigned short* __restrict__ Aadj, float* __restrict__ invdeg) {
    int t = threadIdx.x;
    int row = blockIdx.x * 8 + (t >> 5);
    int u = t & 31;
    uint4 w = reinterpret_cast<const uint4*>(Acnt)[(size_t)row * 32 + u];
    unsigned int wa[4] = { w.x, w.y, w.z, w.w };
    unsigned short out[16];
    float sum = 0.f;
#pragma unroll
    for (int i = 0; i < 4; i++) {
#pragma unroll
        for (int bb = 0; bb < 4; bb++) {
            float fv = (float)((wa[i] >> (8 * bb)) & 0xffu);
            sum += fv;
            out[4 * i + bb] = f2b(fv);         // exact for ints <= 256
        }
    }
    unsigned int pw[8];
#pragma unroll
    for (int i = 0; i < 8; i++)
        pw[i] = (unsigned int)out[2 * i] | ((unsigned int)out[2 * i + 1] << 16);
    uint4* dst = reinterpret_cast<uint4*>(Aadj + (size_t)row * 512 + u * 16);
    uint4 s0 = { pw[0], pw[1], pw[2], pw[3] }, s1 = { pw[4], pw[5], pw[6], pw[7] };
    dst[0] = s0; dst[1] = s1;
#pragma unroll
    for (int d = 1; d < 32; d <<= 1) sum += __shfl_xor(sum, d, 64);
    if (u == 0) invdeg[row] = 1.0f / fmaxf(sum, 1.0f);
}

// ------------- transpose + cast both weights: fp32 [256][C] -> bf16 [C][256] -------------
__global__ void transpose_cast2_kernel(const float* __restrict__ Wf, const float* __restrict__ Wp,
                                       unsigned short* __restrict__ WfT, unsigned short* __restrict__ WpT) {
    __shared__ float tl[32][33];
    int tx = threadIdx.x, ty = threadIdx.y;  // (32, 8)
    int bx = blockIdx.x;
    const float* in; unsigned short* out; int C, cb;
    if (bx < DD / 32) { in = Wf; out = WfT; C = DD; cb = bx; }
    else              { in = Wp; out = WpT; C = AS; cb = bx - DD / 32; }
    int c0 = cb * 32, r0 = blockIdx.y * 32;
    for (int i = 0; i < 4; i++)
        tl[ty + 8 * i][tx] = in[(size_t)(r0 + ty + 8 * i) * C + c0 + tx];
    __syncthreads();
    for (int i = 0; i < 4; i++)
        out[(size_t)(c0 + ty + 8 * i) * 256 + r0 + tx] = f2b(tl[tx][ty + 8 * i]);
}

// ---- agg_h via MFMA: msg[dst][c] = sum_src A[dst][src] h[src][c]; /deg -> bundle upper ----
__global__ __launch_bounds__(256) void agg_h_mfma_kernel(
    const unsigned short* __restrict__ Aadj, const unsigned short* __restrict__ hT,
    const float* __restrict__ invdeg, unsigned short* __restrict__ bundle) {
    __shared__ alignas(16) unsigned short lA[64 * 512];   // 64 dst rows x 512 src (64 KB)
    int tid = threadIdx.x, bx = blockIdx.x;
    int r0 = bx * 64, g = bx >> 3;
    int wv = tid >> 6, lane = tid & 63, q = lane >> 4, lm = lane & 15;
    int mw = wv >> 1, nw = wv & 1;
#pragma unroll
    for (int j = 0; j < 16; j++) {
        int u = tid + 256 * j;
        int row = u >> 6, cu = (u & 63) ^ (row & 7);
        gload16(Aadj + (size_t)(r0 + row) * 512 + cu * 8, &lA[u * 8]);
    }
    floatx4 acc[2][4];
#pragma unroll
    for (int mt = 0; mt < 2; mt++)
#pragma unroll
        for (int nt = 0; nt < 4; nt++) acc[mt][nt] = (floatx4)0.f;
    __syncthreads();

    const unsigned short* Bb = hT + (size_t)(64 * nw + lm) * NN + g * 512 + (q << 3);
    short8 bF[2][4];
#pragma unroll
    for (int nt = 0; nt < 4; nt++)
        bF[0][nt] = *reinterpret_cast<const short8*>(Bb + (size_t)16 * nt * NN);
    for (int ki = 0; ki < 16; ki++) {
        if (ki < 15) {
#pragma unroll
            for (int nt = 0; nt < 4; nt++)
                bF[(ki + 1) & 1][nt] =
                    *reinterpret_cast<const short8*>(Bb + (size_t)16 * nt * NN + (ki + 1) * 32);
        }
        short8 aF[2];
        int swz = (4 * ki + q) ^ (lm & 7);
#pragma unroll
        for (int mt = 0; mt < 2; mt++)
            aF[mt] = *reinterpret_cast<const short8*>(&lA[((32 * mw + 16 * mt + lm) * 64 + swz) * 8]);
#pragma unroll
        for (int mt = 0; mt < 2; mt++)
#pragma unroll
            for (int nt = 0; nt < 4; nt++)
                acc[mt][nt] = __builtin_amdgcn_mfma_f32_16x16x32_bf16(aF[mt], bF[ki & 1][nt],
                                                                      acc[mt][nt], 0, 0, 0);
    }
#pragma unroll
    for (int mt = 0; mt < 2; mt++)
#pragma unroll
        for (int r = 0; r < 4; r++) {
            int row = 32 * mw + 16 * mt + 4 * q + r;
            float inv = invdeg[r0 + row];
#pragma unroll
            for (int nt = 0; nt < 4; nt++)
                bundle[(size_t)(r0 + row) * 256 + 128 + 64 * nw + 16 * nt + lm] =
                    f2b(acc[mt][nt][r] * inv);
        }
}

// ------- feat GEMM (MFMA) + bias + L2norm + relu -> featT bf16 [col][node] -------
__global__ __launch_bounds__(256) void feat_mfma_kernel(
    const unsigned short* __restrict__ bundle, const unsigned short* __restrict__ WfT,
    const float* __restrict__ bfe, unsigned short* __restrict__ featT) {
    __shared__ alignas(16) unsigned short lA[512 * 8];
    __shared__ alignas(16) unsigned short lB[512 * 8];
    __shared__ float red[256];
    __shared__ alignas(16) unsigned short fT[128 * 136];
    int tid = threadIdx.x;
    int r0 = blockIdx.x * 128;
    int wv = tid >> 6, lane = tid & 63;
    int mw = wv >> 1, nw = wv & 1, q = lane >> 4, lm = lane & 15;
    int rowS0 = tid >> 2,         cS0 = (tid & 3) ^ ((rowS0 >> 1) & 3);
    int rowS1 = (tid + 256) >> 2, cS1 = ((tid + 256) & 3) ^ ((rowS1 >> 1) & 3);
    int swz = q ^ ((lm >> 1) & 3);

    floatx4 acc[4][4];
#pragma unroll
    for (int mi = 0; mi < 4; mi++)
#pragma unroll
        for (int ni = 0; ni < 4; ni++) acc[mi][ni] = (floatx4)0.f;

    for (int k0 = 0; k0 < 256; k0 += 32) {
        gload16(bundle + (size_t)(r0 + rowS0) * 256 + k0 + 8 * cS0, &lA[tid * 8]);
        gload16(bundle + (size_t)(r0 + rowS1) * 256 + k0 + 8 * cS1, &lA[(tid + 256) * 8]);
        gload16(WfT + (size_t)rowS0 * 256 + k0 + 8 * cS0, &lB[tid * 8]);
        gload16(WfT + (size_t)rowS1 * 256 + k0 + 8 * cS1, &lB[(tid + 256) * 8]);
        __syncthreads();
        short8 aF[4], bF[4];
#pragma unroll
        for (int mi = 0; mi < 4; mi++)
            aF[mi] = *reinterpret_cast<const short8*>(&lA[((64 * mw + 16 * mi + lm) * 4 + swz) * 8]);
#pragma unroll
        for (int ni = 0; ni < 4; ni++)
            bF[ni] = *reinterpret_cast<const short8*>(&lB[((64 * nw + 16 * ni + lm) * 4 + swz) * 8]);
#pragma unroll
        for (int mi = 0; mi < 4; mi++)
#pragma unroll
            for (int ni = 0; ni < 4; ni++)
                acc[mi][ni] = __builtin_amdgcn_mfma_f32_16x16x32_bf16(aF[mi], bF[ni], acc[mi][ni], 0, 0, 0);
        __syncthreads();
    }
#pragma unroll
    for (int ni = 0; ni < 4; ni++) {
        float bv = bfe[64 * nw + 16 * ni + lm];
#pragma unroll
        for (int mi = 0; mi < 4; mi++)
#pragma unroll
            for (int r = 0; r < 4; r++) acc[mi][ni][r] += bv;
    }
#pragma unroll
    for (int mi = 0; mi < 4; mi++)
#pragma unroll
        for (int r = 0; r < 4; r++) {
            float p = 0.f;
#pragma unroll
            for (int ni = 0; ni < 4; ni++) p += acc[mi][ni][r] * acc[mi][ni][r];
            p += __shfl_xor(p, 1, 64);
            p += __shfl_xor(p, 2, 64);
            p += __shfl_xor(p, 4, 64);
            p += __shfl_xor(p, 8, 64);
            if (lm == 0) red[nw * 128 + 64 * mw + 16 * mi + 4 * q + r] = p;
        }
    __syncthreads();
#pragma unroll
    for (int mi = 0; mi < 4; mi++) {
        float rrn[4];
#pragma unroll
        for (int r = 0; r < 4; r++) {
            int rl = 64 * mw + 16 * mi + 4 * q + r;
            rrn[r] = 1.0f / fmaxf(sqrtf(red[rl] + red[128 + rl]), 1e-12f);
        }
#pragma unroll
        for (int ni = 0; ni < 4; ni++) {
            int col = 64 * nw + 16 * ni + lm;
            ushort4v pk = { f2b(fmaxf(acc[mi][ni][0] * rrn[0], 0.f)),
                            f2b(fmaxf(acc[mi][ni][1] * rrn[1], 0.f)),
                            f2b(fmaxf(acc[mi][ni][2] * rrn[2], 0.f)),
                            f2b(fmaxf(acc[mi][ni][3] * rrn[3], 0.f)) };
            *reinterpret_cast<ushort4v*>(&fT[col * 136 + 64 * mw + 16 * mi + 4 * q]) = pk;
        }
    }
    __syncthreads();
    {
        int col = tid >> 1, half = tid & 1;
        const uint4* src = reinterpret_cast<const uint4*>(&fT[col * 136 + half * 64]);
        uint4* dst = reinterpret_cast<uint4*>(featT + (size_t)col * NN + r0 + half * 64);
#pragma unroll
        for (int i = 0; i < 8; i++) dst[i] = src[i];
    }
}

// -------- pool GEMM fused: A-resident, B streamed, ssq in regs, norm+softmax -> sT ----
__global__ __launch_bounds__(256) void pool_fused_kernel(
    const unsigned short* __restrict__ bundle, const unsigned short* __restrict__ WpT,
    const float* __restrict__ bp, unsigned short* __restrict__ sT) {
    __shared__ alignas(16) unsigned short lA[2048 * 8];  // 64 rows x 256 K (32 KB)
    __shared__ float raw[64 * 68];
    __shared__ float ssq_l[4 * 64];
    __shared__ float rn_l[64];
    int tid = threadIdx.x, bx = blockIdx.x;
    int r0 = bx * 64, g = bx >> 3;
    int wv = tid >> 6, lane = tid & 63, q = lane >> 4, lm = lane & 15;

#pragma unroll
    for (int j = 0; j < 8; j++) {
        int u = tid + 256 * j;
        int row = u >> 5;
        int chunk = (u & 31) ^ (row & 7);
        gload16(bundle + (size_t)(r0 + row) * 256 + chunk * 8, &lA[u * 8]);
    }
    float ssqacc[4][4];
#pragma unroll
    for (int mi = 0; mi < 4; mi++)
#pragma unroll
        for (int r = 0; r < 4; r++) ssqacc[mi][r] = 0.f;
    __syncthreads();

    for (int nc8 = 0; nc8 < 8; nc8++) {
        int nc = 4 * nc8 + wv;
        const unsigned short* Bb = WpT + ((size_t)(nc * 64 + lm) << 8) + (q << 3);
        short8 bF[2][4];
#pragma unroll
        for (int ni = 0; ni < 4; ni++)
            bF[0][ni] = *reinterpret_cast<const short8*>(Bb + (ni << 12));
        floatx4 acc[4][4];
#pragma unroll
        for (int mi = 0; mi < 4; mi++)
#pragma unroll
            for (int ni = 0; ni < 4; ni++) acc[mi][ni] = (floatx4)0.f;
#pragma unroll
        for (int k = 0; k < 8; k++) {
            if (k < 7) {
#pragma unroll
                for (int ni = 0; ni < 4; ni++)
                    bF[(k + 1) & 1][ni] =
                        *reinterpret_cast<const short8*>(Bb + (ni << 12) + ((k + 1) << 5));
            }
            short8 aF[4];
            int swz = (4 * k + q) ^ (lm & 7);
#pragma unroll
            for (int mi = 0; mi < 4; mi++)
                aF[mi] = *reinterpret_cast<const short8*>(&lA[((16 * mi + lm) * 32 + swz) * 8]);
#pragma unroll
            for (int mi = 0; mi < 4; mi++)
#pragma unroll
                for (int ni = 0; ni < 4; ni++)
                    acc[mi][ni] = __builtin_amdgcn_mfma_f32_16x16x32_bf16(aF[mi], bF[k & 1][ni],
                                                                          acc[mi][ni], 0, 0, 0);
        }
        float bv[4];
#pragma unroll
        for (int ni = 0; ni < 4; ni++) bv[ni] = bp[nc * 64 + 16 * ni + lm];
#pragma unroll
        for (int mi = 0; mi < 4; mi++)
#pragma unroll
            for (int r = 0; r < 4; r++) {
                float p = 0.f;
#pragma unroll
                for (int ni = 0; ni < 4; ni++) {
                    acc[mi][ni][r] += bv[ni];
                    p += acc[mi][ni][r] * acc[mi][ni][r];
                }
                ssqacc[mi][r] += p;
            }
        if (nc == g) {
#pragma unroll
            for (int mi = 0; mi < 4; mi++)
#pragma unroll
                for (int ni = 0; ni < 4; ni++)
#pragma unroll
                    for (int r = 0; r < 4; r++)
                        raw[(16 * mi + 4 * q + r) * 68 + 16 * ni + lm] = acc[mi][ni][r];
        }
    }
#pragma unroll
    for (int mi = 0; mi < 4; mi++)
#pragma unroll
        for (int r = 0; r < 4; r++) {
            float p = ssqacc[mi][r];
            p += __shfl_xor(p, 1, 64);
            p += __shfl_xor(p, 2, 64);
            p += __shfl_xor(p, 4, 64);
            p += __shfl_xor(p, 8, 64);
            if (lm == 0) ssq_l[wv * 64 + 16 * mi + 4 * q + r] = p;
        }
    __syncthreads();
    if (tid < 64)
        rn_l[tid] = 1.0f / fmaxf(sqrtf(ssq_l[tid] + ssq_l[64 + tid] + ssq_l[128 + tid] +
                                       ssq_l[192 + tid]), 1e-12f);
    __syncthreads();
    {   // softmax over 64 in-graph cols: 4 threads per row
        int row = tid >> 2, j = tid & 3;
        int nloc = ((bx & 7) << 6) + row;
        float rn = rn_l[row];
        float v[16];
        float mx = -1e30f;
#pragma unroll
        for (int c4 = 0; c4 < 4; c4++) {
            float4 rv = *reinterpret_cast<const float4*>(&raw[row * 68 + 16 * j + 4 * c4]);
            v[4 * c4 + 0] = fmaxf(rv.x * rn, 0.f);
            v[4 * c4 + 1] = fmaxf(rv.y * rn, 0.f);
            v[4 * c4 + 2] = fmaxf(rv.z * rn, 0.f);
            v[4 * c4 + 3] = fmaxf(rv.w * rn, 0.f);
        }
#pragma unroll
        for (int c = 0; c < 16; c++) mx = fmaxf(mx, v[c]);
        mx = fmaxf(mx, __shfl_xor(mx, 1, 64));
        mx = fmaxf(mx, __shfl_xor(mx, 2, 64));
        float z = 0.f;
#pragma unroll
        for (int c = 0; c < 16; c++) { v[c] = __expf(v[c] - mx); z += v[c]; }
        z += __shfl_xor(z, 1, 64);
        z += __shfl_xor(z, 2, 64);
        float iz = 1.0f / z;
#pragma unroll
        for (int c4 = 0; c4 < 4; c4++) {
            size_t tb = (size_t)(g * KC + 16 * j + 4 * c4) * NPER + nloc;
            sT[tb] = f2b(v[4 * c4 + 0] * iz);
            sT[tb + NPER] = f2b(v[4 * c4 + 1] * iz);
            sT[tb + 2 * NPER] = f2b(v[4 * c4 + 2] * iz);
            sT[tb + 3 * NPER] = f2b(v[4 * c4 + 3] * iz);
        }
    }
}

// ---- a_s via MFMA: asT[cl][dst] = sum_src sT[cl][src] * A[dst][src] ----
__global__ __launch_bounds__(256) void as_mfma_kernel(
    const unsigned short* __restrict__ sT, const unsigned short* __restrict__ Aadj,
    unsigned short* __restrict__ asT) {
    __shared__ alignas(16) unsigned short lS[64 * 512];   // 64 cl x 512 src (64 KB)
    int tid = threadIdx.x, bx = blockIdx.x;
    int g = bx >> 1, half = bx & 1;
    int wv = tid >> 6, lane = tid & 63, q = lane >> 4, lm = lane & 15;
#pragma unroll
    for (int j = 0; j < 16; j++) {
        int u = tid + 256 * j;
        int row = u >> 6, cu = (u & 63) ^ (row & 7);
        gload16(sT + (size_t)(g * KC + row) * NPER + cu * 8, &lS[u * 8]);
    }
    floatx4 acc[4][4];
#pragma unroll
    for (int mi = 0; mi < 4; mi++)
#pragma unroll
        for (int nt = 0; nt < 4; nt++) acc[mi][nt] = (floatx4)0.f;
    __syncthreads();

    int dbase = half * 256 + wv * 64;   // this wave's 64 dst
    const unsigned short* Bb = Aadj + (size_t)(g * 512 + dbase + lm) * 512 + (q << 3);
    short8 bF[2][4];
#pragma unroll
    for (int nt = 0; nt < 4; nt++)
        bF[0][nt] = *reinterpret_cast<const short8*>(Bb + (size_t)16 * nt * 512);
    for (int ki = 0; ki < 16; ki++) {
        if (ki < 15) {
#pragma unroll
            for (int nt = 0; nt < 4; nt++)
                bF[(ki + 1) & 1][nt] =
                    *reinterpret_cast<const short8*>(Bb + (size_t)16 * nt * 512 + (ki + 1) * 32);
        }
        short8 aF[4];
        int swz = (4 * ki + q) ^ (lm & 7);
#pragma unroll
        for (int mi = 0; mi < 4; mi++)
            aF[mi] = *reinterpret_cast<const short8*>(&lS[((16 * mi + lm) * 64 + swz) * 8]);
#pragma unroll
        for (int mi = 0; mi < 4; mi++)
#pragma unroll
            for (int nt = 0; nt < 4; nt++)
                acc[mi][nt] = __builtin_amdgcn_mfma_f32_16x16x32_bf16(aF[mi], bF[ki & 1][nt],
                                                                      acc[mi][nt], 0, 0, 0);
    }
#pragma unroll
    for (int mi = 0; mi < 4; mi++)
#pragma unroll
        for (int r = 0; r < 4; r++) {
            int row = 16 * mi + 4 * q + r;
#pragma unroll
            for (int nt = 0; nt < 4; nt++)
                asT[(size_t)(g * KC + row) * NPER + dbase + 16 * nt + lm] = f2b(acc[mi][nt][r]);
        }
}

// ------- fused h_new + adj via MFMA: per (graph, 128-node chunk) block ---------
__global__ __launch_bounds__(256) void hnew_adj_kernel(
    const unsigned short* __restrict__ sT, const unsigned short* __restrict__ featT,
    const unsigned short* __restrict__ asT, float* __restrict__ adjf,
    float* __restrict__ hnewf) {
    __shared__ alignas(16) unsigned short lS[1024 * 8];
    __shared__ alignas(16) unsigned short lF[2048 * 8];
    __shared__ alignas(16) unsigned short lAS[1024 * 8];
    int tid = threadIdx.x;
    int ch = blockIdx.x, g = blockIdx.y;
    int k0 = g * NPER + ch * 128;
    int wv = tid >> 6, lane = tid & 63, q = lane >> 4, lm = lane & 15;

#pragma unroll
    for (int j = 0; j < 4; j++) {
        int u = tid + 256 * j;
        int row = u >> 4, cu = (u & 15) ^ (row & 15);
        gload16(sT + (size_t)(g * KC + row) * NPER + ch * 128 + cu * 8, &lS[u * 8]);
    }
#pragma unroll
    for (int j = 0; j < 8; j++) {
        int u = tid + 256 * j;
        int row = u >> 4, cu = (u & 15) ^ (row & 15);
        gload16(featT + (size_t)row * NN + k0 + cu * 8, &lF[u * 8]);
    }
#pragma unroll
    for (int j = 0; j < 4; j++) {
        int u = tid + 256 * j;
        int row = u >> 4, cu = (u & 15) ^ (row & 15);
        gload16(asT + (size_t)(g * KC + row) * NPER + ch * 128 + cu * 8, &lAS[u * 8]);
    }
    floatx4 acc[4][4];
#pragma unroll
    for (int mi = 0; mi < 4; mi++)
#pragma unroll
        for (int ni = 0; ni < 4; ni++) acc[mi][ni] = (floatx4)0.f;
    __syncthreads();

    bool isH = (wv < 2);
    for (int ks = 0; ks < 4; ks++) {
        if (!isH && (ks >> 1) != (wv & 1)) continue;
        short8 aF[4], bF[4];
#pragma unroll
        for (int mi = 0; mi < 4; mi++)
            aF[mi] = *reinterpret_cast<const short8*>(
                &lS[((16 * mi + lm) * 16 + ((4 * ks + q) ^ lm)) * 8]);
        if (isH) {
#pragma unroll
            for (int ni = 0; ni < 4; ni++)
                bF[ni] = *reinterpret_cast<const short8*>(
                    &lF[((64 * wv + 16 * ni + lm) * 16 + ((4 * ks + q) ^ lm)) * 8]);
        } else {
#pragma unroll
            for (int ni = 0; ni < 4; ni++)
                bF[ni] = *reinterpret_cast<const short8*>(
                    &lAS[((16 * ni + lm) * 16 + ((4 * ks + q) ^ lm)) * 8]);
        }
#pragma unroll
        for (int mi = 0; mi < 4; mi++)
#pragma unroll
            for (int ni = 0; ni < 4; ni++)
                acc[mi][ni] = __builtin_amdgcn_mfma_f32_16x16x32_bf16(aF[mi], bF[ni], acc[mi][ni], 0, 0, 0);
    }
    if (isH) {
#pragma unroll
        for (int mi = 0; mi < 4; mi++)
#pragma unroll
            for (int ni = 0; ni < 4; ni++)
#pragma unroll
                for (int r = 0; r < 4; r++)
                    atomicAdd(&hnewf[(size_t)(g * KC + 16 * mi + 4 * q + r) * DD +
                                     64 * wv + 16 * ni + lm], acc[mi][ni][r]);
    } else {
#pragma unroll
        for (int mi = 0; mi < 4; mi++)
#pragma unroll
            for (int ni = 0; ni < 4; ni++)
#pragma unroll
                for (int r = 0; r < 4; r++)
                    atomicAdd(&adjf[(size_t)(g * KC + 16 * mi + 4 * q + r) * AS +
                                    g * KC + 16 * ni + lm], acc[mi][ni][r]);
    }
}

extern "C" void kernel_launch(void* const* d_in, const int* in_sizes, int n_in,
                              void* d_out, int out_size, void* d_ws, size_t ws_size,
                              hipStream_t stream) {
    const float* h   = (const float*)d_in[0];
    const float* Wf  = (const float*)d_in[1];
    const float* bfe = (const float*)d_in[2];
    const float* Wp  = (const float*)d_in[3];
    const float* bp  = (const float*)d_in[4];
    const int* esrc  = (const int*)d_in[5];
    const int* edst  = (const int*)d_in[6];

    float* adjf  = (float*)d_out;
    float* hnewf = adjf + (size_t)AS * AS;

    unsigned short* bundle = (unsigned short*)d_ws;        // NN*256 bf16
    unsigned short* WfT   = bundle + (size_t)NN * 256;     // 128*256
    unsigned short* WpT   = WfT + 128 * 256;               // 2048*256
    unsigned short* sT    = WpT + (size_t)AS * 256;        // NN*KC   [g*64+cl][node]
    unsigned short* asT   = sT + (size_t)NN * KC;          // NN*KC
    unsigned short* featT = asT + (size_t)NN * KC;         // DD*NN
    unsigned short* hT    = featT + (size_t)DD * NN;       // DD*NN
    unsigned short* Aadj  = hT + (size_t)DD * NN;          // NN*512 bf16 (16 MB)
    float* invdeg = (float*)(Aadj + (size_t)NN * 512);     // NN
    unsigned int* Acnt = (unsigned int*)(invdeg + NN);     // NN*512 bytes (8.4 MB)

    hipMemsetAsync(Acnt, 0, (size_t)NN * 512, stream);
    hipMemsetAsync(d_out, 0, ((size_t)AS * AS + (size_t)AS * DD) * sizeof(float), stream);

    prep_kernel<<<128 + EE / 256, 256, 0, stream>>>(h, bundle, hT, esrc, edst, Acnt);
    conv_kernel<<<NN / 8, 256, 0, stream>>>(Acnt, Aadj, invdeg);
    transpose_cast2_kernel<<<dim3(DD / 32 + AS / 32, 256 / 32), dim3(32, 8), 0, stream>>>(
        Wf, Wp, WfT, WpT);
    agg_h_mfma_kernel<<<NN / 64, 256, 0, stream>>>(Aadj, hT, invdeg, bundle);
    feat_mfma_kernel<<<NN / 128, 256, 0, stream>>>(bundle, WfT, bfe, featT);
    pool_fused_kernel<<<NN / 64, 256, 0, stream>>>(bundle, WpT, bp, sT);
    as_mfma_kernel<<<NB * 2, 256, 0, stream>>>(sT, Aadj, asT);
    hnew_adj_kernel<<<dim3(4, NB), 256, 0, stream>>>(sT, featT, asT, adjf, hnewf);
}